// Round 9
// baseline (334.541 us; speedup 1.0000x reference)
//
#include <hip/hip_runtime.h>
#include <hip/hip_bf16.h>

#define EMBED 1024
#define HEADS 16
#define HDIM  64
#define BATCH 2
#define SEQ   2048
#define MTOT  (BATCH*SEQ)   // 4096

typedef __attribute__((ext_vector_type(8))) short bf16x8;
typedef __attribute__((ext_vector_type(4))) short bf16x4;
typedef __attribute__((ext_vector_type(4))) float f32x4;
typedef __attribute__((ext_vector_type(8))) unsigned short u16x8;
typedef __attribute__((ext_vector_type(2))) unsigned u32x2;
typedef __attribute__((ext_vector_type(4))) unsigned u32x4;

// native RNE f32->bf16 pair: compiles to one v_cvt_pk_bf16_f32
__device__ __forceinline__ unsigned pack2(float lo, float hi) {
    __hip_bfloat162 h = __float22bfloat162_rn(make_float2(lo, hi));
    unsigned u;
    __builtin_memcpy(&u, &h, sizeof(u));
    return u;
}
__device__ __forceinline__ unsigned short f2bf(float f) {
    __hip_bfloat16 h = __float2bfloat16(f);
    unsigned short u;
    __builtin_memcpy(&u, &h, sizeof(u));
    return u;
}
__device__ __forceinline__ u16x8 cvt8(float4 a, float4 b) {
    u32x4 r;
    r[0] = pack2(a.x, a.y);
    r[1] = pack2(a.z, a.w);
    r[2] = pack2(b.x, b.y);
    r[3] = pack2(b.z, b.w);
    return __builtin_bit_cast(u16x8, r);
}

__device__ __forceinline__ f32x4 mfma16(bf16x4 a, bf16x4 b, f32x4 c) {
#if __has_builtin(__builtin_amdgcn_mfma_f32_16x16x16bf16_1k)
    return __builtin_amdgcn_mfma_f32_16x16x16bf16_1k(a, b, c, 0, 0, 0);
#else
    f32x4 d;
    asm volatile("v_mfma_f32_16x16x16_bf16 %0, %1, %2, %3"
                 : "=v"(d) : "v"(a), "v"(b), "v"(c));
    return d;
#endif
}

// ------------------------------------------------------------------
// Kernel 1: QKV projection (unchanged from R8; K pre-scaled by
// C = 0.125*log2e so attention scores are in exp2 units).
// ------------------------------------------------------------------
__global__ __launch_bounds__(256, 2) void qkv_proj(
    const float* __restrict__ x,
    const float* __restrict__ wq, const float* __restrict__ bq,
    const float* __restrict__ wk, const float* __restrict__ bk,
    const float* __restrict__ wv, const float* __restrict__ bv,
    unsigned short* __restrict__ qo,
    unsigned short* __restrict__ ko,
    unsigned short* __restrict__ vto)
{
    const int which = blockIdx.z;
    const float* __restrict__ w    = (which == 0) ? wq : (which == 1) ? wk : wv;
    const float* __restrict__ bias = (which == 0) ? bq : (which == 1) ? bk : bv;
    const float kscale = (which == 1) ? 0.18033688f : 1.0f;  // 0.125*log2e

    const int m0 = blockIdx.x * 128;
    const int n0 = blockIdx.y * 128;

    __shared__ unsigned short a_lds[128][40];
    __shared__ unsigned short b_lds[128][40];

    const int tid  = threadIdx.x;
    const int lane = tid & 63;
    const int wid  = tid >> 6;
    const int wr   = wid >> 1, wc = wid & 1;
    const int lq   = lane & 15;
    const int lg   = lane >> 4;

    f32x4 acc[4][4] = {};

    const int srow = tid >> 2;
    const int scol = (tid & 3) * 8;

    for (int k0 = 0; k0 < EMBED; k0 += 32) {
        #pragma unroll
        for (int p = 0; p < 2; ++p) {
            const int r = srow + p * 64;
            const float4* sa = (const float4*)(x + (size_t)(m0 + r) * EMBED + k0 + scol);
            *(u16x8*)&a_lds[r][scol] = cvt8(sa[0], sa[1]);
            const float4* sb = (const float4*)(w + (size_t)(n0 + r) * EMBED + k0 + scol);
            *(u16x8*)&b_lds[r][scol] = cvt8(sb[0], sb[1]);
        }
        __syncthreads();
        bf16x8 af[4], bfr[4];
        #pragma unroll
        for (int i = 0; i < 4; ++i)
            af[i] = *(const bf16x8*)&a_lds[wr*64 + i*16 + lq][lg*8];
        #pragma unroll
        for (int j = 0; j < 4; ++j)
            bfr[j] = *(const bf16x8*)&b_lds[wc*64 + j*16 + lq][lg*8];
        #pragma unroll
        for (int i = 0; i < 4; ++i)
            #pragma unroll
            for (int j = 0; j < 4; ++j)
                acc[i][j] = __builtin_amdgcn_mfma_f32_16x16x32_bf16(af[i], bfr[j], acc[i][j], 0, 0, 0);
        __syncthreads();
    }

    #pragma unroll
    for (int j = 0; j < 4; ++j) {
        const int nn = n0 + wc*64 + j*16 + lq;
        const float bsv = bias[nn];
        const int h = nn >> 6, d = nn & (HDIM-1);
        #pragma unroll
        for (int i = 0; i < 4; ++i) {
            const int mmb = m0 + wr*64 + i*16 + lg*4;
            const int b = mmb >> 11;
            const int s = mmb & (SEQ-1);
            const size_t bh = (size_t)(b*HEADS + h);
            if (which == 2) {
                u32x2 ov;
                ov[0] = pack2(acc[i][j][0] + bsv, acc[i][j][1] + bsv);
                ov[1] = pack2(acc[i][j][2] + bsv, acc[i][j][3] + bsv);
                *(u32x2*)&vto[(bh*HDIM + d)*SEQ + s] = ov;
            } else {
                unsigned short* o = (which == 0) ? qo : ko;
                #pragma unroll
                for (int r = 0; r < 4; ++r)
                    o[(bh*SEQ + (s + r))*HDIM + d] = f2bf((acc[i][j][r] + bsv) * kscale);
            }
        }
    }
}

// ------------------------------------------------------------------
// Kernel 2: flash attention v8.
//  - K: staged in LDS (XOR-swizzled, double-buffered) as before.
//  - V: *** direct global->register *** (16 x b64 per tile; contiguous
//    8B/lane thanks to the [BH][D][S] V^T layout; L2-resident under the
//    XCD swizzle). Moves V traffic off the saturated LDS pipe (73%
//    util) onto the idle VMEM/L2 pipe; kills the V-read bank conflicts.
//  - Per-tile schedule: V-issue(t) -> K-load(t+1) -> QK^T+softmax
//    (covers ~200cy L2 latency) -> PV (vmcnt leaves K in flight) ->
//    K ds_write -> barrier.
//  - No online max (R8); P = exp2(s) directly.
// ------------------------------------------------------------------
__global__ __launch_bounds__(256, 4) void attn(
    const unsigned short* __restrict__ q,
    const unsigned short* __restrict__ k,
    const unsigned short* __restrict__ vt,
    unsigned short* __restrict__ ctx)
{
    __shared__ __align__(16) unsigned char sm[2 * 8192];   // K tiles only

    const int bid   = blockIdx.x;          // 0..1023
    const int xcd   = bid & 7;
    const int local = bid >> 3;            // 0..127
    const int bh    = xcd * 4 + (local >> 5);
    const int q0    = (local & 31) * 64;
    const int b     = bh >> 4;
    const int h     = bh & (HEADS - 1);
    const int tid   = threadIdx.x;
    const int wv    = tid >> 6;
    const int lane  = tid & 63;
    const int lq = lane & 15, lg = lane >> 4;

    const unsigned short* qb = q  + (size_t)bh * SEQ * HDIM;
    const unsigned short* kb = k  + (size_t)bh * SEQ * HDIM;
    const unsigned short* vb = vt + (size_t)bh * HDIM * SEQ;

    // K LDS offsets (swizzled), unchanged
    const int swz    = (lq & 7) << 4;
    const int kread0 = lq*128 + ((lg*16)      ^ swz);   // + sub*2048
    const int kread1 = lq*128 + ((lg*16 + 64) ^ swz);   // + sub*2048

    const int wrow = tid >> 3;             // 0..31
    const int woff = wrow*128 + ((((tid & 7) * 16)) ^ ((wrow & 7) << 4));

    const int scol = (tid & 7) * 8;
    const unsigned short* kp = kb + (size_t)wrow * HDIM + scol;

    // V^T per-lane base pointers: frag (sub,i) = V^T[i*16+lq][kv0+sub*16+lg*4]
    const unsigned short* vbp[4];
    #pragma unroll
    for (int i = 0; i < 4; ++i)
        vbp[i] = vb + (size_t)(i*16 + lq) * SEQ + lg*4;

    bf16x8 qf[2];
    #pragma unroll
    for (int hh = 0; hh < 2; ++hh)
        qf[hh] = *(const bf16x8*)(qb + (size_t)(q0 + wv*16 + lq) * HDIM + hh*32 + lg*8);

    f32x4 o[4] = {};
    float lr = 0.f;

    u16x8 kr0, kr1;
    bf16x4 vf[4][4];   // [sub][i]

#define LOADT() do {                                                           \
    kr0 = *(const u16x8*)(kp);                                                 \
    kr1 = *(const u16x8*)(kp + 32*HDIM);                                       \
} while (0)

#define WRITET(BF) do {                                                        \
    *(u16x8*)(sm + (BF)*8192 +        woff) = kr0;                             \
    *(u16x8*)(sm + (BF)*8192 + 4096 + woff) = kr1;                             \
} while (0)

#define VISSUE() do {                                                          \
    _Pragma("unroll")                                                          \
    for (int i = 0; i < 4; ++i) {                                              \
        vf[0][i] = *(const bf16x4*)(vbp[i]);                                   \
        vf[1][i] = *(const bf16x4*)(vbp[i] + 16);                              \
        vf[2][i] = *(const bf16x4*)(vbp[i] + 32);                              \
        vf[3][i] = *(const bf16x4*)(vbp[i] + 48);                              \
        vbp[i] += 64;                                                          \
    }                                                                          \
} while (0)

#define COMPUTE(BF) do {                                                       \
    f32x4 s_[4];                                                               \
    _Pragma("unroll")                                                          \
    for (int sub = 0; sub < 4; ++sub) {                                        \
        bf16x8 k0 = *(const bf16x8*)(sm + (BF)*8192 + sub*2048 + kread0);      \
        bf16x8 k1 = *(const bf16x8*)(sm + (BF)*8192 + sub*2048 + kread1);      \
        f32x4 z = {};                                                          \
        z = __builtin_amdgcn_mfma_f32_16x16x32_bf16(k0, qf[0], z, 0, 0, 0);    \
        z = __builtin_amdgcn_mfma_f32_16x16x32_bf16(k1, qf[1], z, 0, 0, 0);    \
        s_[sub] = z;                                                           \
    }                                                                          \
    bf16x4 pf[4];                                                              \
    float psum = 0.f;                                                          \
    _Pragma("unroll")                                                          \
    for (int sub = 0; sub < 4; ++sub) {                                        \
        f32x4 pv;                                                              \
        _Pragma("unroll")                                                      \
        for (int r = 0; r < 4; ++r) pv[r] = exp2f(s_[sub][r]);                 \
        psum += (pv[0] + pv[1]) + (pv[2] + pv[3]);                             \
        u32x2 pk;                                                              \
        pk[0] = pack2(pv[0], pv[1]);                                           \
        pk[1] = pack2(pv[2], pv[3]);                                           \
        pf[sub] = __builtin_bit_cast(bf16x4, pk);                              \
    }                                                                          \
    lr += psum;                                                                \
    _Pragma("unroll")                                                          \
    for (int sub = 0; sub < 4; ++sub) {                                        \
        _Pragma("unroll")                                                      \
        for (int i = 0; i < 4; ++i)                                            \
            o[i] = mfma16(vf[sub][i], pf[sub], o[i]);                          \
    }                                                                          \
} while (0)

    // prologue: stage K tile 0
    LOADT();
    WRITET(0);
    __syncthreads();
    kp += 64 * HDIM;

    for (int t2 = 0; t2 < 16; ++t2) {
        {   // even tile -> K buffer 0
            const int t = 2 * t2;
            VISSUE();                       // V(t) into regs (L2, ~200cy to cover)
            if (t < 31) LOADT();            // K(t+1)
            COMPUTE(0);
            if (t < 31) {
                WRITET(1);
                __syncthreads();
                kp += 64 * HDIM;
            }
        }
        {   // odd tile -> K buffer 1
            const int t = 2 * t2 + 1;
            VISSUE();
            if (t < 31) LOADT();
            COMPUTE(1);
            if (t < 31) {
                WRITET(0);
                __syncthreads();
                kp += 64 * HDIM;
            }
        }
    }

#undef LOADT
#undef WRITET
#undef VISSUE
#undef COMPUTE

    float lm = lr + __shfl_xor(lr, 16);
    lm += __shfl_xor(lm, 32);
    const float inv = 1.0f / lm;
    unsigned short* cb = ctx + ((size_t)(b*SEQ + q0 + wv*16 + lq)) * EMBED + h*HDIM;
    #pragma unroll
    for (int i = 0; i < 4; ++i) {
        u32x2 ov;
        ov[0] = pack2(o[i][0] * inv, o[i][1] * inv);
        ov[1] = pack2(o[i][2] * inv, o[i][3] * inv);
        *(u32x2*)(cb + i*16 + lg*4) = ov;
    }
}

// ------------------------------------------------------------------
// Kernel 3: output projection (unchanged).
// ------------------------------------------------------------------
__global__ __launch_bounds__(256, 2) void out_proj(
    const unsigned short* __restrict__ ctx,
    const float* __restrict__ wo, const float* __restrict__ bo,
    float* __restrict__ out)
{
    const int m0 = blockIdx.x * 128;
    const int n0 = blockIdx.y * 128;

    __shared__ unsigned short a_lds[128][40];
    __shared__ unsigned short b_lds[128][40];

    const int tid  = threadIdx.x;
    const int lane = tid & 63;
    const int wid  = tid >> 6;
    const int wr   = wid >> 1, wc = wid & 1;
    const int lq   = lane & 15;
    const int lg   = lane >> 4;

    f32x4 acc[4][4] = {};

    const int srow = tid >> 2;
    const int scol = (tid & 3) * 8;

    for (int k0 = 0; k0 < EMBED; k0 += 32) {
        #pragma unroll
        for (int p = 0; p < 2; ++p) {
            const int r = srow + p * 64;
            *(u16x8*)&a_lds[r][scol] =
                *(const u16x8*)(ctx + (size_t)(m0 + r) * EMBED + k0 + scol);
            const float4* sb = (const float4*)(wo + (size_t)(n0 + r) * EMBED + k0 + scol);
            *(u16x8*)&b_lds[r][scol] = cvt8(sb[0], sb[1]);
        }
        __syncthreads();
        bf16x8 af[4], bfr[4];
        #pragma unroll
        for (int i = 0; i < 4; ++i)
            af[i] = *(const bf16x8*)&a_lds[wr*64 + i*16 + lq][lg*8];
        #pragma unroll
        for (int j = 0; j < 4; ++j)
            bfr[j] = *(const bf16x8*)&b_lds[wc*64 + j*16 + lq][lg*8];
        #pragma unroll
        for (int i = 0; i < 4; ++i)
            #pragma unroll
            for (int j = 0; j < 4; ++j)
                acc[i][j] = __builtin_amdgcn_mfma_f32_16x16x32_bf16(af[i], bfr[j], acc[i][j], 0, 0, 0);
        __syncthreads();
    }

    #pragma unroll
    for (int j = 0; j < 4; ++j) {
        const int nn = n0 + wc*64 + j*16 + lq;
        const float bsv = bo[nn];
        #pragma unroll
        for (int i = 0; i < 4; ++i) {
            const int mm = m0 + wr*64 + i*16 + lg*4;
            #pragma unroll
            for (int r = 0; r < 4; ++r)
                out[(size_t)(mm + r) * EMBED + nn] = acc[i][j][r] + bsv;
        }
    }
}

extern "C" void kernel_launch(void* const* d_in, const int* in_sizes, int n_in,
                              void* d_out, int out_size, void* d_ws, size_t ws_size,
                              hipStream_t stream) {
    const float* x  = (const float*)d_in[0];
    const float* wq = (const float*)d_in[1];
    const float* bq = (const float*)d_in[2];
    const float* wk = (const float*)d_in[3];
    const float* bk = (const float*)d_in[4];
    const float* wv = (const float*)d_in[5];
    const float* bv = (const float*)d_in[6];
    const float* wo = (const float*)d_in[7];
    const float* bo = (const float*)d_in[8];
    float* out = (float*)d_out;

    const size_t NELEM = (size_t)MTOT * EMBED;   // 4M elements
    unsigned short* q_ws   = (unsigned short*)d_ws;
    unsigned short* k_ws   = q_ws  + NELEM;
    unsigned short* vt_ws  = k_ws  + NELEM;
    unsigned short* ctx_ws = vt_ws + NELEM;      // total 32 MB bf16

    qkv_proj<<<dim3(MTOT/128, EMBED/128, 3), 256, 0, stream>>>(
        x, wq, bq, wk, bk, wv, bv, q_ws, k_ws, vt_ws);
    attn<<<dim3(SEQ/64 * BATCH*HEADS), 256, 0, stream>>>(q_ws, k_ws, vt_ws, ctx_ws);
    out_proj<<<dim3(MTOT/128, EMBED/128), 256, 0, stream>>>(ctx_ws, wo, bo, out);
}

// Round 10
// 150.403 us; speedup vs baseline: 2.2243x; 2.2243x over previous
//
#include <hip/hip_runtime.h>
#include <hip/hip_bf16.h>

#define EMBED 1024
#define HEADS 16
#define HDIM  64
#define BATCH 2
#define SEQ   2048
#define MTOT  (BATCH*SEQ)   // 4096

typedef __attribute__((ext_vector_type(8))) short bf16x8;
typedef __attribute__((ext_vector_type(4))) short bf16x4;
typedef __attribute__((ext_vector_type(4))) float f32x4;
typedef __attribute__((ext_vector_type(8))) unsigned short u16x8;
typedef __attribute__((ext_vector_type(2))) unsigned u32x2;
typedef __attribute__((ext_vector_type(4))) unsigned u32x4;

// native RNE f32->bf16 pair: compiles to one v_cvt_pk_bf16_f32
__device__ __forceinline__ unsigned pack2(float lo, float hi) {
    __hip_bfloat162 h = __float22bfloat162_rn(make_float2(lo, hi));
    unsigned u;
    __builtin_memcpy(&u, &h, sizeof(u));
    return u;
}
__device__ __forceinline__ unsigned short f2bf(float f) {
    __hip_bfloat16 h = __float2bfloat16(f);
    unsigned short u;
    __builtin_memcpy(&u, &h, sizeof(u));
    return u;
}
__device__ __forceinline__ u16x8 cvt8(float4 a, float4 b) {
    u32x4 r;
    r[0] = pack2(a.x, a.y);
    r[1] = pack2(a.z, a.w);
    r[2] = pack2(b.x, b.y);
    r[3] = pack2(b.z, b.w);
    return __builtin_bit_cast(u16x8, r);
}

__device__ __forceinline__ f32x4 mfma16(bf16x4 a, bf16x4 b, f32x4 c) {
#if __has_builtin(__builtin_amdgcn_mfma_f32_16x16x16bf16_1k)
    return __builtin_amdgcn_mfma_f32_16x16x16bf16_1k(a, b, c, 0, 0, 0);
#else
    f32x4 d;
    asm volatile("v_mfma_f32_16x16x16_bf16 %0, %1, %2, %3"
                 : "=v"(d) : "v"(a), "v"(b), "v"(c));
    return d;
#endif
}

// ------------------------------------------------------------------
// Kernel 1: QKV projection (unchanged from R8; K pre-scaled by
// C = 0.125*log2e so attention scores are in exp2 units).
// ------------------------------------------------------------------
__global__ __launch_bounds__(256, 2) void qkv_proj(
    const float* __restrict__ x,
    const float* __restrict__ wq, const float* __restrict__ bq,
    const float* __restrict__ wk, const float* __restrict__ bk,
    const float* __restrict__ wv, const float* __restrict__ bv,
    unsigned short* __restrict__ qo,
    unsigned short* __restrict__ ko,
    unsigned short* __restrict__ vto)
{
    const int which = blockIdx.z;
    const float* __restrict__ w    = (which == 0) ? wq : (which == 1) ? wk : wv;
    const float* __restrict__ bias = (which == 0) ? bq : (which == 1) ? bk : bv;
    const float kscale = (which == 1) ? 0.18033688f : 1.0f;  // 0.125*log2e

    const int m0 = blockIdx.x * 128;
    const int n0 = blockIdx.y * 128;

    __shared__ unsigned short a_lds[128][40];
    __shared__ unsigned short b_lds[128][40];

    const int tid  = threadIdx.x;
    const int lane = tid & 63;
    const int wid  = tid >> 6;
    const int wr   = wid >> 1, wc = wid & 1;
    const int lq   = lane & 15;
    const int lg   = lane >> 4;

    f32x4 acc[4][4] = {};

    const int srow = tid >> 2;
    const int scol = (tid & 3) * 8;

    for (int k0 = 0; k0 < EMBED; k0 += 32) {
        #pragma unroll
        for (int p = 0; p < 2; ++p) {
            const int r = srow + p * 64;
            const float4* sa = (const float4*)(x + (size_t)(m0 + r) * EMBED + k0 + scol);
            *(u16x8*)&a_lds[r][scol] = cvt8(sa[0], sa[1]);
            const float4* sb = (const float4*)(w + (size_t)(n0 + r) * EMBED + k0 + scol);
            *(u16x8*)&b_lds[r][scol] = cvt8(sb[0], sb[1]);
        }
        __syncthreads();
        bf16x8 af[4], bfr[4];
        #pragma unroll
        for (int i = 0; i < 4; ++i)
            af[i] = *(const bf16x8*)&a_lds[wr*64 + i*16 + lq][lg*8];
        #pragma unroll
        for (int j = 0; j < 4; ++j)
            bfr[j] = *(const bf16x8*)&b_lds[wc*64 + j*16 + lq][lg*8];
        #pragma unroll
        for (int i = 0; i < 4; ++i)
            #pragma unroll
            for (int j = 0; j < 4; ++j)
                acc[i][j] = __builtin_amdgcn_mfma_f32_16x16x32_bf16(af[i], bfr[j], acc[i][j], 0, 0, 0);
        __syncthreads();
    }

    #pragma unroll
    for (int j = 0; j < 4; ++j) {
        const int nn = n0 + wc*64 + j*16 + lq;
        const float bsv = bias[nn];
        const int h = nn >> 6, d = nn & (HDIM-1);
        #pragma unroll
        for (int i = 0; i < 4; ++i) {
            const int mmb = m0 + wr*64 + i*16 + lg*4;
            const int b = mmb >> 11;
            const int s = mmb & (SEQ-1);
            const size_t bh = (size_t)(b*HEADS + h);
            if (which == 2) {
                u32x2 ov;
                ov[0] = pack2(acc[i][j][0] + bsv, acc[i][j][1] + bsv);
                ov[1] = pack2(acc[i][j][2] + bsv, acc[i][j][3] + bsv);
                *(u32x2*)&vto[(bh*HDIM + d)*SEQ + s] = ov;
            } else {
                unsigned short* o = (which == 0) ? qo : ko;
                #pragma unroll
                for (int r = 0; r < 4; ++r)
                    o[(bh*SEQ + (s + r))*HDIM + d] = f2bf((acc[i][j][r] + bsv) * kscale);
            }
        }
    }
}

// ------------------------------------------------------------------
// Kernel 2: flash attention v9 = R8 structure (K AND V staged in LDS,
// double-buffered, 4 waves x 16 q-rows, no online max) with one change:
//  *** V column-permuted in LDS *** : element (d, s) stored at
//  col' = ((s>>2)&3)*16 + (s>>4)*4 + (s&3). Each lane's four kv-subtile
//  A-frags become 16 CONSECUTIVE elements -> V reads are 2 x b128 per
//  output frag (8 total/tile, was 16 x b64), and with the (row&7)<<4
//  XOR swizzle every 4-bank group gets exactly 8 lanes (bank-minimal,
//  conflict-free). V writes become 4 x b64 (verified element-exact).
// ------------------------------------------------------------------
__global__ __launch_bounds__(256, 4) void attn(
    const unsigned short* __restrict__ q,
    const unsigned short* __restrict__ k,
    const unsigned short* __restrict__ vt,
    unsigned short* __restrict__ ctx)
{
    __shared__ __align__(16) unsigned char sm[2 * 16384];  // per buf: K 8KB, V 8KB

    const int bid   = blockIdx.x;          // 0..1023
    const int xcd   = bid & 7;
    const int local = bid >> 3;            // 0..127
    const int bh    = xcd * 4 + (local >> 5);
    const int q0    = (local & 31) * 64;
    const int b     = bh >> 4;
    const int h     = bh & (HEADS - 1);
    const int tid   = threadIdx.x;
    const int wv    = tid >> 6;
    const int lane  = tid & 63;
    const int lq = lane & 15, lg = lane >> 4;

    const unsigned short* qb = q  + (size_t)bh * SEQ * HDIM;
    const unsigned short* kb = k  + (size_t)bh * SEQ * HDIM;
    const unsigned short* vb = vt + (size_t)bh * HDIM * SEQ;

    // K LDS read offsets (swizzled), unchanged from R8
    const int swz    = (lq & 7) << 4;
    const int kread0 = lq*128 + ((lg*16)      ^ swz);   // + sub*2048
    const int kread1 = lq*128 + ((lg*16 + 64) ^ swz);   // + sub*2048

    // V LDS read offsets: per frag i, 32B run at col lg*16 (permuted layout)
    const int vrd0 = lq*128 + ((lg*32)      ^ swz);     // + i*2048, subs 0-1
    const int vrd1 = lq*128 + ((lg*32 + 16) ^ swz);     // + i*2048, subs 2-3

    // staging
    const int wrow = tid >> 3;             // 0..31
    const int c8   = tid & 7;              // 0..7
    const int wswz = (wrow & 7) << 4;
    const int woff = wrow*128 + ((c8 * 16) ^ wswz);     // K write (b128)
    const int vin0 = (c8 & 1)*64 + (c8 >> 1)*8;         // V write inner bytes
    const int woffV0 = wrow*128 + (vin0        ^ wswz); // s-group j=0..3
    const int woffV1 = wrow*128 + ((vin0 + 32) ^ wswz); // s-group j=4..7

    const int scol = c8 * 8;
    const unsigned short* kp = kb + (size_t)wrow * HDIM + scol;
    const unsigned short* vp = vb + (size_t)wrow * SEQ + scol;

    bf16x8 qf[2];
    #pragma unroll
    for (int hh = 0; hh < 2; ++hh)
        qf[hh] = *(const bf16x8*)(qb + (size_t)(q0 + wv*16 + lq) * HDIM + hh*32 + lg*8);

    f32x4 o[4] = {};
    float lr = 0.f;

    u16x8 kr0, kr1, vr0, vr1;

#define LOADT() do {                                                           \
    kr0 = *(const u16x8*)(kp);                                                 \
    kr1 = *(const u16x8*)(kp + 32*HDIM);                                       \
    vr0 = *(const u16x8*)(vp);                                                 \
    vr1 = *(const u16x8*)(vp + 32*SEQ);                                        \
} while (0)

#define WRITET(BF) do {                                                        \
    unsigned char* smb = sm + (BF)*16384;                                      \
    *(u16x8*)(smb +        woff) = kr0;                                        \
    *(u16x8*)(smb + 4096 + woff) = kr1;                                        \
    u32x4 t0 = __builtin_bit_cast(u32x4, vr0);                                 \
    u32x4 t1 = __builtin_bit_cast(u32x4, vr1);                                 \
    u32x2 hlf;                                                                 \
    hlf[0] = t0[0]; hlf[1] = t0[1];                                            \
    *(u32x2*)(smb +  8192 + woffV0) = hlf;                                     \
    hlf[0] = t0[2]; hlf[1] = t0[3];                                            \
    *(u32x2*)(smb +  8192 + woffV1) = hlf;                                     \
    hlf[0] = t1[0]; hlf[1] = t1[1];                                            \
    *(u32x2*)(smb + 12288 + woffV0) = hlf;                                     \
    hlf[0] = t1[2]; hlf[1] = t1[3];                                            \
    *(u32x2*)(smb + 12288 + woffV1) = hlf;                                     \
} while (0)

#define COMPUTE(BF) do {                                                       \
    const unsigned char* smb = sm + (BF)*16384;                                \
    f32x4 s_[4];                                                               \
    _Pragma("unroll")                                                          \
    for (int sub = 0; sub < 4; ++sub) {                                        \
        bf16x8 k0 = *(const bf16x8*)(smb + sub*2048 + kread0);                 \
        bf16x8 k1 = *(const bf16x8*)(smb + sub*2048 + kread1);                 \
        f32x4 z = {};                                                          \
        z = __builtin_amdgcn_mfma_f32_16x16x32_bf16(k0, qf[0], z, 0, 0, 0);    \
        z = __builtin_amdgcn_mfma_f32_16x16x32_bf16(k1, qf[1], z, 0, 0, 0);    \
        s_[sub] = z;                                                           \
    }                                                                          \
    bf16x4 pf[4];                                                              \
    float psum = 0.f;                                                          \
    _Pragma("unroll")                                                          \
    for (int sub = 0; sub < 4; ++sub) {                                        \
        f32x4 pv;                                                              \
        _Pragma("unroll")                                                      \
        for (int r = 0; r < 4; ++r) pv[r] = exp2f(s_[sub][r]);                 \
        psum += (pv[0] + pv[1]) + (pv[2] + pv[3]);                             \
        u32x2 pk;                                                              \
        pk[0] = pack2(pv[0], pv[1]);                                           \
        pk[1] = pack2(pv[2], pv[3]);                                           \
        pf[sub] = __builtin_bit_cast(bf16x4, pk);                              \
    }                                                                          \
    lr += psum;                                                                \
    _Pragma("unroll")                                                          \
    for (int i = 0; i < 4; ++i) {                                              \
        bf16x8 v01 = *(const bf16x8*)(smb + 8192 + i*2048 + vrd0);             \
        bf16x8 v23 = *(const bf16x8*)(smb + 8192 + i*2048 + vrd1);             \
        u32x4 a01 = __builtin_bit_cast(u32x4, v01);                            \
        u32x4 a23 = __builtin_bit_cast(u32x4, v23);                            \
        u32x2 hw;                                                              \
        hw[0] = a01[0]; hw[1] = a01[1];                                        \
        o[i] = mfma16(__builtin_bit_cast(bf16x4, hw), pf[0], o[i]);            \
        hw[0] = a01[2]; hw[1] = a01[3];                                        \
        o[i] = mfma16(__builtin_bit_cast(bf16x4, hw), pf[1], o[i]);            \
        hw[0] = a23[0]; hw[1] = a23[1];                                        \
        o[i] = mfma16(__builtin_bit_cast(bf16x4, hw), pf[2], o[i]);            \
        hw[0] = a23[2]; hw[1] = a23[3];                                        \
        o[i] = mfma16(__builtin_bit_cast(bf16x4, hw), pf[3], o[i]);            \
    }                                                                          \
} while (0)

    // prologue: stage tile 0
    LOADT();
    WRITET(0);
    __syncthreads();
    kp += 64 * HDIM;
    vp += 64;

    for (int t2 = 0; t2 < 16; ++t2) {
        {   // even tile -> buffer 0
            const int t = 2 * t2;
            if (t < 31) LOADT();
            COMPUTE(0);
            if (t < 31) {
                WRITET(1);
                __syncthreads();
                kp += 64 * HDIM;
                vp += 64;
            }
        }
        {   // odd tile -> buffer 1
            const int t = 2 * t2 + 1;
            if (t < 31) LOADT();
            COMPUTE(1);
            if (t < 31) {
                WRITET(0);
                __syncthreads();
                kp += 64 * HDIM;
                vp += 64;
            }
        }
    }

#undef LOADT
#undef WRITET
#undef COMPUTE

    float lm = lr + __shfl_xor(lr, 16);
    lm += __shfl_xor(lm, 32);
    const float inv = 1.0f / lm;
    unsigned short* cb = ctx + ((size_t)(b*SEQ + q0 + wv*16 + lq)) * EMBED + h*HDIM;
    #pragma unroll
    for (int i = 0; i < 4; ++i) {
        u32x2 ov;
        ov[0] = pack2(o[i][0] * inv, o[i][1] * inv);
        ov[1] = pack2(o[i][2] * inv, o[i][3] * inv);
        *(u32x2*)(cb + i*16 + lg*4) = ov;
    }
}

// ------------------------------------------------------------------
// Kernel 3: output projection (unchanged).
// ------------------------------------------------------------------
__global__ __launch_bounds__(256, 2) void out_proj(
    const unsigned short* __restrict__ ctx,
    const float* __restrict__ wo, const float* __restrict__ bo,
    float* __restrict__ out)
{
    const int m0 = blockIdx.x * 128;
    const int n0 = blockIdx.y * 128;

    __shared__ unsigned short a_lds[128][40];
    __shared__ unsigned short b_lds[128][40];

    const int tid  = threadIdx.x;
    const int lane = tid & 63;
    const int wid  = tid >> 6;
    const int wr   = wid >> 1, wc = wid & 1;
    const int lq   = lane & 15;
    const int lg   = lane >> 4;

    f32x4 acc[4][4] = {};

    const int srow = tid >> 2;
    const int scol = (tid & 3) * 8;

    for (int k0 = 0; k0 < EMBED; k0 += 32) {
        #pragma unroll
        for (int p = 0; p < 2; ++p) {
            const int r = srow + p * 64;
            *(u16x8*)&a_lds[r][scol] =
                *(const u16x8*)(ctx + (size_t)(m0 + r) * EMBED + k0 + scol);
            const float4* sb = (const float4*)(wo + (size_t)(n0 + r) * EMBED + k0 + scol);
            *(u16x8*)&b_lds[r][scol] = cvt8(sb[0], sb[1]);
        }
        __syncthreads();
        bf16x8 af[4], bfr[4];
        #pragma unroll
        for (int i = 0; i < 4; ++i)
            af[i] = *(const bf16x8*)&a_lds[wr*64 + i*16 + lq][lg*8];
        #pragma unroll
        for (int j = 0; j < 4; ++j)
            bfr[j] = *(const bf16x8*)&b_lds[wc*64 + j*16 + lq][lg*8];
        #pragma unroll
        for (int i = 0; i < 4; ++i)
            #pragma unroll
            for (int j = 0; j < 4; ++j)
                acc[i][j] = __builtin_amdgcn_mfma_f32_16x16x32_bf16(af[i], bfr[j], acc[i][j], 0, 0, 0);
        __syncthreads();
    }

    #pragma unroll
    for (int j = 0; j < 4; ++j) {
        const int nn = n0 + wc*64 + j*16 + lq;
        const float bsv = bo[nn];
        #pragma unroll
        for (int i = 0; i < 4; ++i) {
            const int mm = m0 + wr*64 + i*16 + lg*4;
            #pragma unroll
            for (int r = 0; r < 4; ++r)
                out[(size_t)(mm + r) * EMBED + nn] = acc[i][j][r] + bsv;
        }
    }
}

extern "C" void kernel_launch(void* const* d_in, const int* in_sizes, int n_in,
                              void* d_out, int out_size, void* d_ws, size_t ws_size,
                              hipStream_t stream) {
    const float* x  = (const float*)d_in[0];
    const float* wq = (const float*)d_in[1];
    const float* bq = (const float*)d_in[2];
    const float* wk = (const float*)d_in[3];
    const float* bk = (const float*)d_in[4];
    const float* wv = (const float*)d_in[5];
    const float* bv = (const float*)d_in[6];
    const float* wo = (const float*)d_in[7];
    const float* bo = (const float*)d_in[8];
    float* out = (float*)d_out;

    const size_t NELEM = (size_t)MTOT * EMBED;   // 4M elements
    unsigned short* q_ws   = (unsigned short*)d_ws;
    unsigned short* k_ws   = q_ws  + NELEM;
    unsigned short* vt_ws  = k_ws  + NELEM;
    unsigned short* ctx_ws = vt_ws + NELEM;      // total 32 MB bf16

    qkv_proj<<<dim3(MTOT/128, EMBED/128, 3), 256, 0, stream>>>(
        x, wq, bq, wk, bk, wv, bv, q_ws, k_ws, vt_ws);
    attn<<<dim3(SEQ/64 * BATCH*HEADS), 256, 0, stream>>>(q_ws, k_ws, vt_ws, ctx_ws);
    out_proj<<<dim3(MTOT/128, EMBED/128), 256, 0, stream>>>(ctx_ws, wo, bo, out);
}

// Round 11
// 145.472 us; speedup vs baseline: 2.2997x; 1.0339x over previous
//
#include <hip/hip_runtime.h>
#include <hip/hip_bf16.h>

#define EMBED 1024
#define HEADS 16
#define HDIM  64
#define BATCH 2
#define SEQ   2048
#define MTOT  (BATCH*SEQ)   // 4096

typedef __attribute__((ext_vector_type(8))) short bf16x8;
typedef __attribute__((ext_vector_type(4))) short bf16x4;
typedef __attribute__((ext_vector_type(4))) float f32x4;
typedef __attribute__((ext_vector_type(8))) unsigned short u16x8;
typedef __attribute__((ext_vector_type(2))) unsigned u32x2;
typedef __attribute__((ext_vector_type(4))) unsigned u32x4;

// native RNE f32->bf16 pair: compiles to one v_cvt_pk_bf16_f32
__device__ __forceinline__ unsigned pack2(float lo, float hi) {
    __hip_bfloat162 h = __float22bfloat162_rn(make_float2(lo, hi));
    unsigned u;
    __builtin_memcpy(&u, &h, sizeof(u));
    return u;
}
__device__ __forceinline__ unsigned short f2bf(float f) {
    __hip_bfloat16 h = __float2bfloat16(f);
    unsigned short u;
    __builtin_memcpy(&u, &h, sizeof(u));
    return u;
}

__device__ __forceinline__ f32x4 mfma16(bf16x4 a, bf16x4 b, f32x4 c) {
#if __has_builtin(__builtin_amdgcn_mfma_f32_16x16x16bf16_1k)
    return __builtin_amdgcn_mfma_f32_16x16x16bf16_1k(a, b, c, 0, 0, 0);
#else
    f32x4 d;
    asm volatile("v_mfma_f32_16x16x16_bf16 %0, %1, %2, %3"
                 : "=v"(d) : "v"(a), "v"(b), "v"(c));
    return d;
#endif
}

// ------------------------------------------------------------------
// Kernel 0: one-shot f32 -> bf16 conversion of x and the 4 weight
// matrices. Memory-bound (~51 MB). Downstream GEMMs then read HALF
// the bytes from L2/L3 and do ZERO conversion VALU in their K-loops.
// ------------------------------------------------------------------
__global__ __launch_bounds__(256) void preconvert(
    const float* __restrict__ x,
    const float* __restrict__ wq, const float* __restrict__ wk,
    const float* __restrict__ wv, const float* __restrict__ wo,
    unsigned short* __restrict__ xb,
    unsigned short* __restrict__ wqb, unsigned short* __restrict__ wkb,
    unsigned short* __restrict__ wvb, unsigned short* __restrict__ wob)
{
    const int NX = (MTOT * EMBED) / 4;            // 1M float4 of x
    const int NW = (EMBED * EMBED) / 4;           // 256K float4 per weight
    int idx = blockIdx.x * 256 + threadIdx.x;     // 0 .. NX + 4*NW - 1
    const float* src;
    unsigned short* dst;
    int off;
    if (idx < NX) {
        src = x; dst = xb; off = idx;
    } else {
        int r = idx - NX;
        int w = r / NW;
        off = r - w * NW;
        src = (w == 0) ? wq : (w == 1) ? wk : (w == 2) ? wv : wo;
        dst = (w == 0) ? wqb : (w == 1) ? wkb : (w == 2) ? wvb : wob;
    }
    float4 v = ((const float4*)src)[off];
    u32x2 o;
    o[0] = pack2(v.x, v.y);
    o[1] = pack2(v.z, v.w);
    *(u32x2*)(dst + (size_t)off * 4) = o;
}

// ------------------------------------------------------------------
// Kernel 1: QKV projection, all-bf16 inputs (pre-converted). K output
// scaled by C = 0.125*log2e in the epilogue (scores in exp2 units).
// ------------------------------------------------------------------
__global__ __launch_bounds__(256, 2) void qkv_proj(
    const unsigned short* __restrict__ xb,
    const unsigned short* __restrict__ wqb, const float* __restrict__ bq,
    const unsigned short* __restrict__ wkb, const float* __restrict__ bk,
    const unsigned short* __restrict__ wvb, const float* __restrict__ bv,
    unsigned short* __restrict__ qo,
    unsigned short* __restrict__ ko,
    unsigned short* __restrict__ vto)
{
    const int which = blockIdx.z;
    const unsigned short* __restrict__ w =
        (which == 0) ? wqb : (which == 1) ? wkb : wvb;
    const float* __restrict__ bias = (which == 0) ? bq : (which == 1) ? bk : bv;
    const float kscale = (which == 1) ? 0.18033688f : 1.0f;  // 0.125*log2e

    const int m0 = blockIdx.x * 128;
    const int n0 = blockIdx.y * 128;

    __shared__ unsigned short a_lds[128][40];
    __shared__ unsigned short b_lds[128][40];

    const int tid  = threadIdx.x;
    const int lane = tid & 63;
    const int wid  = tid >> 6;
    const int wr   = wid >> 1, wc = wid & 1;
    const int lq   = lane & 15;
    const int lg   = lane >> 4;

    f32x4 acc[4][4] = {};

    const int srow = tid >> 2;
    const int scol = (tid & 3) * 8;

    for (int k0 = 0; k0 < EMBED; k0 += 32) {
        #pragma unroll
        for (int p = 0; p < 2; ++p) {
            const int r = srow + p * 64;
            *(u16x8*)&a_lds[r][scol] =
                *(const u16x8*)(xb + (size_t)(m0 + r) * EMBED + k0 + scol);
            *(u16x8*)&b_lds[r][scol] =
                *(const u16x8*)(w + (size_t)(n0 + r) * EMBED + k0 + scol);
        }
        __syncthreads();
        bf16x8 af[4], bfr[4];
        #pragma unroll
        for (int i = 0; i < 4; ++i)
            af[i] = *(const bf16x8*)&a_lds[wr*64 + i*16 + lq][lg*8];
        #pragma unroll
        for (int j = 0; j < 4; ++j)
            bfr[j] = *(const bf16x8*)&b_lds[wc*64 + j*16 + lq][lg*8];
        #pragma unroll
        for (int i = 0; i < 4; ++i)
            #pragma unroll
            for (int j = 0; j < 4; ++j)
                acc[i][j] = __builtin_amdgcn_mfma_f32_16x16x32_bf16(af[i], bfr[j], acc[i][j], 0, 0, 0);
        __syncthreads();
    }

    #pragma unroll
    for (int j = 0; j < 4; ++j) {
        const int nn = n0 + wc*64 + j*16 + lq;
        const float bsv = bias[nn];
        const int h = nn >> 6, d = nn & (HDIM-1);
        #pragma unroll
        for (int i = 0; i < 4; ++i) {
            const int mmb = m0 + wr*64 + i*16 + lg*4;
            const int b = mmb >> 11;
            const int s = mmb & (SEQ-1);
            const size_t bh = (size_t)(b*HEADS + h);
            if (which == 2) {
                u32x2 ov;
                ov[0] = pack2(acc[i][j][0] + bsv, acc[i][j][1] + bsv);
                ov[1] = pack2(acc[i][j][2] + bsv, acc[i][j][3] + bsv);
                *(u32x2*)&vto[(bh*HDIM + d)*SEQ + s] = ov;
            } else {
                unsigned short* o = (which == 0) ? qo : ko;
                #pragma unroll
                for (int r = 0; r < 4; ++r)
                    o[(bh*SEQ + (s + r))*HDIM + d] = f2bf((acc[i][j][r] + bsv) * kscale);
            }
        }
    }
}

// ------------------------------------------------------------------
// Kernel 2: flash attention (unchanged from R10 best: K + permuted V
// in XOR-swizzled LDS, double-buffered, no online max).
// ------------------------------------------------------------------
__global__ __launch_bounds__(256, 4) void attn(
    const unsigned short* __restrict__ q,
    const unsigned short* __restrict__ k,
    const unsigned short* __restrict__ vt,
    unsigned short* __restrict__ ctx)
{
    __shared__ __align__(16) unsigned char sm[2 * 16384];  // per buf: K 8KB, V 8KB

    const int bid   = blockIdx.x;          // 0..1023
    const int xcd   = bid & 7;
    const int local = bid >> 3;            // 0..127
    const int bh    = xcd * 4 + (local >> 5);
    const int q0    = (local & 31) * 64;
    const int b     = bh >> 4;
    const int h     = bh & (HEADS - 1);
    const int tid   = threadIdx.x;
    const int wv    = tid >> 6;
    const int lane  = tid & 63;
    const int lq = lane & 15, lg = lane >> 4;

    const unsigned short* qb = q  + (size_t)bh * SEQ * HDIM;
    const unsigned short* kb = k  + (size_t)bh * SEQ * HDIM;
    const unsigned short* vb = vt + (size_t)bh * HDIM * SEQ;

    const int swz    = (lq & 7) << 4;
    const int kread0 = lq*128 + ((lg*16)      ^ swz);   // + sub*2048
    const int kread1 = lq*128 + ((lg*16 + 64) ^ swz);   // + sub*2048

    const int vrd0 = lq*128 + ((lg*32)      ^ swz);     // + i*2048, subs 0-1
    const int vrd1 = lq*128 + ((lg*32 + 16) ^ swz);     // + i*2048, subs 2-3

    const int wrow = tid >> 3;             // 0..31
    const int c8   = tid & 7;              // 0..7
    const int wswz = (wrow & 7) << 4;
    const int woff = wrow*128 + ((c8 * 16) ^ wswz);     // K write (b128)
    const int vin0 = (c8 & 1)*64 + (c8 >> 1)*8;         // V write inner bytes
    const int woffV0 = wrow*128 + (vin0        ^ wswz);
    const int woffV1 = wrow*128 + ((vin0 + 32) ^ wswz);

    const int scol = c8 * 8;
    const unsigned short* kp = kb + (size_t)wrow * HDIM + scol;
    const unsigned short* vp = vb + (size_t)wrow * SEQ + scol;

    bf16x8 qf[2];
    #pragma unroll
    for (int hh = 0; hh < 2; ++hh)
        qf[hh] = *(const bf16x8*)(qb + (size_t)(q0 + wv*16 + lq) * HDIM + hh*32 + lg*8);

    f32x4 o[4] = {};
    float lr = 0.f;

    u16x8 kr0, kr1, vr0, vr1;

#define LOADT() do {                                                           \
    kr0 = *(const u16x8*)(kp);                                                 \
    kr1 = *(const u16x8*)(kp + 32*HDIM);                                       \
    vr0 = *(const u16x8*)(vp);                                                 \
    vr1 = *(const u16x8*)(vp + 32*SEQ);                                        \
} while (0)

#define WRITET(BF) do {                                                        \
    unsigned char* smb = sm + (BF)*16384;                                      \
    *(u16x8*)(smb +        woff) = kr0;                                        \
    *(u16x8*)(smb + 4096 + woff) = kr1;                                        \
    u32x4 t0 = __builtin_bit_cast(u32x4, vr0);                                 \
    u32x4 t1 = __builtin_bit_cast(u32x4, vr1);                                 \
    u32x2 hlf;                                                                 \
    hlf[0] = t0[0]; hlf[1] = t0[1];                                            \
    *(u32x2*)(smb +  8192 + woffV0) = hlf;                                     \
    hlf[0] = t0[2]; hlf[1] = t0[3];                                            \
    *(u32x2*)(smb +  8192 + woffV1) = hlf;                                     \
    hlf[0] = t1[0]; hlf[1] = t1[1];                                            \
    *(u32x2*)(smb + 12288 + woffV0) = hlf;                                     \
    hlf[0] = t1[2]; hlf[1] = t1[3];                                            \
    *(u32x2*)(smb + 12288 + woffV1) = hlf;                                     \
} while (0)

#define COMPUTE(BF) do {                                                       \
    const unsigned char* smb = sm + (BF)*16384;                                \
    f32x4 s_[4];                                                               \
    _Pragma("unroll")                                                          \
    for (int sub = 0; sub < 4; ++sub) {                                        \
        bf16x8 k0 = *(const bf16x8*)(smb + sub*2048 + kread0);                 \
        bf16x8 k1 = *(const bf16x8*)(smb + sub*2048 + kread1);                 \
        f32x4 z = {};                                                          \
        z = __builtin_amdgcn_mfma_f32_16x16x32_bf16(k0, qf[0], z, 0, 0, 0);    \
        z = __builtin_amdgcn_mfma_f32_16x16x32_bf16(k1, qf[1], z, 0, 0, 0);    \
        s_[sub] = z;                                                           \
    }                                                                          \
    bf16x4 pf[4];                                                              \
    float psum = 0.f;                                                          \
    _Pragma("unroll")                                                          \
    for (int sub = 0; sub < 4; ++sub) {                                        \
        f32x4 pv;                                                              \
        _Pragma("unroll")                                                      \
        for (int r = 0; r < 4; ++r) pv[r] = exp2f(s_[sub][r]);                 \
        psum += (pv[0] + pv[1]) + (pv[2] + pv[3]);                             \
        u32x2 pk;                                                              \
        pk[0] = pack2(pv[0], pv[1]);                                           \
        pk[1] = pack2(pv[2], pv[3]);                                           \
        pf[sub] = __builtin_bit_cast(bf16x4, pk);                              \
    }                                                                          \
    lr += psum;                                                                \
    _Pragma("unroll")                                                          \
    for (int i = 0; i < 4; ++i) {                                              \
        bf16x8 v01 = *(const bf16x8*)(smb + 8192 + i*2048 + vrd0);             \
        bf16x8 v23 = *(const bf16x8*)(smb + 8192 + i*2048 + vrd1);             \
        u32x4 a01 = __builtin_bit_cast(u32x4, v01);                            \
        u32x4 a23 = __builtin_bit_cast(u32x4, v23);                            \
        u32x2 hw;                                                              \
        hw[0] = a01[0]; hw[1] = a01[1];                                        \
        o[i] = mfma16(__builtin_bit_cast(bf16x4, hw), pf[0], o[i]);            \
        hw[0] = a01[2]; hw[1] = a01[3];                                        \
        o[i] = mfma16(__builtin_bit_cast(bf16x4, hw), pf[1], o[i]);            \
        hw[0] = a23[0]; hw[1] = a23[1];                                        \
        o[i] = mfma16(__builtin_bit_cast(bf16x4, hw), pf[2], o[i]);            \
        hw[0] = a23[2]; hw[1] = a23[3];                                        \
        o[i] = mfma16(__builtin_bit_cast(bf16x4, hw), pf[3], o[i]);            \
    }                                                                          \
} while (0)

    LOADT();
    WRITET(0);
    __syncthreads();
    kp += 64 * HDIM;
    vp += 64;

    for (int t2 = 0; t2 < 16; ++t2) {
        {
            const int t = 2 * t2;
            if (t < 31) LOADT();
            COMPUTE(0);
            if (t < 31) {
                WRITET(1);
                __syncthreads();
                kp += 64 * HDIM;
                vp += 64;
            }
        }
        {
            const int t = 2 * t2 + 1;
            if (t < 31) LOADT();
            COMPUTE(1);
            if (t < 31) {
                WRITET(0);
                __syncthreads();
                kp += 64 * HDIM;
                vp += 64;
            }
        }
    }

#undef LOADT
#undef WRITET
#undef COMPUTE

    float lm = lr + __shfl_xor(lr, 16);
    lm += __shfl_xor(lm, 32);
    const float inv = 1.0f / lm;
    unsigned short* cb = ctx + ((size_t)(b*SEQ + q0 + wv*16 + lq)) * EMBED + h*HDIM;
    #pragma unroll
    for (int i = 0; i < 4; ++i) {
        u32x2 ov;
        ov[0] = pack2(o[i][0] * inv, o[i][1] * inv);
        ov[1] = pack2(o[i][2] * inv, o[i][3] * inv);
        *(u32x2*)(cb + i*16 + lg*4) = ov;
    }
}

// ------------------------------------------------------------------
// Kernel 3: output projection, bf16 weight (pre-converted).
// ------------------------------------------------------------------
__global__ __launch_bounds__(256, 2) void out_proj(
    const unsigned short* __restrict__ ctx,
    const unsigned short* __restrict__ wob, const float* __restrict__ bo,
    float* __restrict__ out)
{
    const int m0 = blockIdx.x * 128;
    const int n0 = blockIdx.y * 128;

    __shared__ unsigned short a_lds[128][40];
    __shared__ unsigned short b_lds[128][40];

    const int tid  = threadIdx.x;
    const int lane = tid & 63;
    const int wid  = tid >> 6;
    const int wr   = wid >> 1, wc = wid & 1;
    const int lq   = lane & 15;
    const int lg   = lane >> 4;

    f32x4 acc[4][4] = {};

    const int srow = tid >> 2;
    const int scol = (tid & 3) * 8;

    for (int k0 = 0; k0 < EMBED; k0 += 32) {
        #pragma unroll
        for (int p = 0; p < 2; ++p) {
            const int r = srow + p * 64;
            *(u16x8*)&a_lds[r][scol] =
                *(const u16x8*)(ctx + (size_t)(m0 + r) * EMBED + k0 + scol);
            *(u16x8*)&b_lds[r][scol] =
                *(const u16x8*)(wob + (size_t)(n0 + r) * EMBED + k0 + scol);
        }
        __syncthreads();
        bf16x8 af[4], bfr[4];
        #pragma unroll
        for (int i = 0; i < 4; ++i)
            af[i] = *(const bf16x8*)&a_lds[wr*64 + i*16 + lq][lg*8];
        #pragma unroll
        for (int j = 0; j < 4; ++j)
            bfr[j] = *(const bf16x8*)&b_lds[wc*64 + j*16 + lq][lg*8];
        #pragma unroll
        for (int i = 0; i < 4; ++i)
            #pragma unroll
            for (int j = 0; j < 4; ++j)
                acc[i][j] = __builtin_amdgcn_mfma_f32_16x16x32_bf16(af[i], bfr[j], acc[i][j], 0, 0, 0);
        __syncthreads();
    }

    #pragma unroll
    for (int j = 0; j < 4; ++j) {
        const int nn = n0 + wc*64 + j*16 + lq;
        const float bsv = bo[nn];
        #pragma unroll
        for (int i = 0; i < 4; ++i) {
            const int mm = m0 + wr*64 + i*16 + lg*4;
            #pragma unroll
            for (int r = 0; r < 4; ++r)
                out[(size_t)(mm + r) * EMBED + nn] = acc[i][j][r] + bsv;
        }
    }
}

extern "C" void kernel_launch(void* const* d_in, const int* in_sizes, int n_in,
                              void* d_out, int out_size, void* d_ws, size_t ws_size,
                              hipStream_t stream) {
    const float* x  = (const float*)d_in[0];
    const float* wq = (const float*)d_in[1];
    const float* bq = (const float*)d_in[2];
    const float* wk = (const float*)d_in[3];
    const float* bk = (const float*)d_in[4];
    const float* wv = (const float*)d_in[5];
    const float* bv = (const float*)d_in[6];
    const float* wo = (const float*)d_in[7];
    const float* bo = (const float*)d_in[8];
    float* out = (float*)d_out;

    const size_t NELEM = (size_t)MTOT * EMBED;   // 4M elements
    const size_t WELEM = (size_t)EMBED * EMBED;  // 1M elements
    unsigned short* q_ws   = (unsigned short*)d_ws;
    unsigned short* k_ws   = q_ws  + NELEM;
    unsigned short* vt_ws  = k_ws  + NELEM;
    unsigned short* ctx_ws = vt_ws + NELEM;
    unsigned short* wqb    = ctx_ws + NELEM;     // +8MB weights block
    unsigned short* wkb    = wqb + WELEM;
    unsigned short* wvb    = wkb + WELEM;
    unsigned short* wob    = wvb + WELEM;        // total 40 MB
    // xb aliases ctx_ws: qkv_proj consumes xb fully before attn writes ctx.
    unsigned short* xb     = ctx_ws;

    const int NCONV = (int)((NELEM + 4 * WELEM) / 4);   // float4 count = 2M
    preconvert<<<dim3(NCONV / 256), 256, 0, stream>>>(
        x, wq, wk, wv, wo, xb, wqb, wkb, wvb, wob);
    qkv_proj<<<dim3(MTOT/128, EMBED/128, 3), 256, 0, stream>>>(
        xb, wqb, bq, wkb, bk, wvb, bv, q_ws, k_ws, vt_ws);
    attn<<<dim3(SEQ/64 * BATCH*HEADS), 256, 0, stream>>>(q_ws, k_ws, vt_ws, ctx_ws);
    out_proj<<<dim3(MTOT/128, EMBED/128), 256, 0, stream>>>(ctx_ws, wob, bo, out);
}

// Round 12
// 138.952 us; speedup vs baseline: 2.4076x; 1.0469x over previous
//
#include <hip/hip_runtime.h>
#include <hip/hip_bf16.h>

#define EMBED 1024
#define HEADS 16
#define HDIM  64
#define BATCH 2
#define SEQ   2048
#define MTOT  (BATCH*SEQ)   // 4096

typedef __attribute__((ext_vector_type(8))) short bf16x8;
typedef __attribute__((ext_vector_type(4))) short bf16x4;
typedef __attribute__((ext_vector_type(4))) float f32x4;
typedef __attribute__((ext_vector_type(8))) unsigned short u16x8;
typedef __attribute__((ext_vector_type(2))) unsigned u32x2;
typedef __attribute__((ext_vector_type(4))) unsigned u32x4;

// native RNE f32->bf16 pair: compiles to one v_cvt_pk_bf16_f32
__device__ __forceinline__ unsigned pack2(float lo, float hi) {
    __hip_bfloat162 h = __float22bfloat162_rn(make_float2(lo, hi));
    unsigned u;
    __builtin_memcpy(&u, &h, sizeof(u));
    return u;
}
__device__ __forceinline__ unsigned short f2bf(float f) {
    __hip_bfloat16 h = __float2bfloat16(f);
    unsigned short u;
    __builtin_memcpy(&u, &h, sizeof(u));
    return u;
}

__device__ __forceinline__ f32x4 mfma16(bf16x4 a, bf16x4 b, f32x4 c) {
#if __has_builtin(__builtin_amdgcn_mfma_f32_16x16x16bf16_1k)
    return __builtin_amdgcn_mfma_f32_16x16x16bf16_1k(a, b, c, 0, 0, 0);
#else
    f32x4 d;
    asm volatile("v_mfma_f32_16x16x16_bf16 %0, %1, %2, %3"
                 : "=v"(d) : "v"(a), "v"(b), "v"(c));
    return d;
#endif
}

// async global->LDS DMA, 16B per lane (dest = lds base + lane*16)
__device__ __forceinline__ void glds16(const void* g, void* l) {
    __builtin_amdgcn_global_load_lds(
        (const __attribute__((address_space(1))) void*)g,
        (__attribute__((address_space(3))) void*)l, 16, 0, 0);
}

// ------------------------------------------------------------------
// Kernel 0: one-shot f32 -> bf16 conversion (unchanged from R11).
// ------------------------------------------------------------------
__global__ __launch_bounds__(256) void preconvert(
    const float* __restrict__ x,
    const float* __restrict__ wq, const float* __restrict__ wk,
    const float* __restrict__ wv, const float* __restrict__ wo,
    unsigned short* __restrict__ xb,
    unsigned short* __restrict__ wqb, unsigned short* __restrict__ wkb,
    unsigned short* __restrict__ wvb, unsigned short* __restrict__ wob)
{
    const int NX = (MTOT * EMBED) / 4;
    const int NW = (EMBED * EMBED) / 4;
    int idx = blockIdx.x * 256 + threadIdx.x;
    const float* src;
    unsigned short* dst;
    int off;
    if (idx < NX) {
        src = x; dst = xb; off = idx;
    } else {
        int r = idx - NX;
        int w = r / NW;
        off = r - w * NW;
        src = (w == 0) ? wq : (w == 1) ? wk : (w == 2) ? wv : wo;
        dst = (w == 0) ? wqb : (w == 1) ? wkb : (w == 2) ? wvb : wob;
    }
    float4 v = ((const float4*)src)[off];
    u32x2 o;
    o[0] = pack2(v.x, v.y);
    o[1] = pack2(v.z, v.w);
    *(u32x2*)(dst + (size_t)off * 4) = o;
}

// ------------------------------------------------------------------
// Kernel 1: QKV projection, m97-style staging: linear LDS [128][32]
// tiles filled by global_load_lds dwordx4 (no staging regs, no
// ds_writes, no per-tile address VALU). Single-buffer 2-barrier loop.
// ------------------------------------------------------------------
__global__ __launch_bounds__(256, 2) void qkv_proj(
    const unsigned short* __restrict__ xb,
    const unsigned short* __restrict__ wqb, const float* __restrict__ bq,
    const unsigned short* __restrict__ wkb, const float* __restrict__ bk,
    const unsigned short* __restrict__ wvb, const float* __restrict__ bv,
    unsigned short* __restrict__ qo,
    unsigned short* __restrict__ ko,
    unsigned short* __restrict__ vto)
{
    const int which = blockIdx.z;
    const unsigned short* __restrict__ w =
        (which == 0) ? wqb : (which == 1) ? wkb : wvb;
    const float* __restrict__ bias = (which == 0) ? bq : (which == 1) ? bk : bv;
    const float kscale = (which == 1) ? 0.18033688f : 1.0f;  // 0.125*log2e

    const int m0 = blockIdx.x * 128;
    const int n0 = blockIdx.y * 128;

    __shared__ __align__(16) unsigned short a_lds[128 * 32];
    __shared__ __align__(16) unsigned short b_lds[128 * 32];

    const int tid  = threadIdx.x;
    const int lane = tid & 63;
    const int wid  = tid >> 6;
    const int wr   = wid >> 1, wc = wid & 1;
    const int lq   = lane & 15;
    const int lg   = lane >> 4;

    f32x4 acc[4][4] = {};

    // staging geometry: wave `wid` DMAs rows [wid*32, wid*32+32) of both
    // tiles; lane covers row srow, elements scol8..scol8+7 (16B).
    const int srow  = wid * 32 + (lane >> 2);
    const int scol8 = (lane & 3) * 8;
    const unsigned short* ap0 = xb + (size_t)(m0 + srow)      * EMBED + scol8;
    const unsigned short* ap1 = xb + (size_t)(m0 + srow + 16) * EMBED + scol8;
    const unsigned short* bp0 = w  + (size_t)(n0 + srow)      * EMBED + scol8;
    const unsigned short* bp1 = w  + (size_t)(n0 + srow + 16) * EMBED + scol8;
    unsigned short* la0 = a_lds + wid * 1024;
    unsigned short* la1 = a_lds + wid * 1024 + 512;
    unsigned short* lb0 = b_lds + wid * 1024;
    unsigned short* lb1 = b_lds + wid * 1024 + 512;

    for (int k0 = 0; k0 < EMBED; k0 += 32) {
        glds16(ap0 + k0, la0);
        glds16(ap1 + k0, la1);
        glds16(bp0 + k0, lb0);
        glds16(bp1 + k0, lb1);
        __syncthreads();
        bf16x8 af[4], bfr[4];
        #pragma unroll
        for (int i = 0; i < 4; ++i)
            af[i] = *(const bf16x8*)&a_lds[(wr*64 + i*16 + lq) * 32 + lg*8];
        #pragma unroll
        for (int j = 0; j < 4; ++j)
            bfr[j] = *(const bf16x8*)&b_lds[(wc*64 + j*16 + lq) * 32 + lg*8];
        #pragma unroll
        for (int i = 0; i < 4; ++i)
            #pragma unroll
            for (int j = 0; j < 4; ++j)
                acc[i][j] = __builtin_amdgcn_mfma_f32_16x16x32_bf16(af[i], bfr[j], acc[i][j], 0, 0, 0);
        __syncthreads();
    }

    #pragma unroll
    for (int j = 0; j < 4; ++j) {
        const int nn = n0 + wc*64 + j*16 + lq;
        const float bsv = bias[nn];
        const int h = nn >> 6, d = nn & (HDIM-1);
        #pragma unroll
        for (int i = 0; i < 4; ++i) {
            const int mmb = m0 + wr*64 + i*16 + lg*4;
            const int b = mmb >> 11;
            const int s = mmb & (SEQ-1);
            const size_t bh = (size_t)(b*HEADS + h);
            if (which == 2) {
                u32x2 ov;
                ov[0] = pack2(acc[i][j][0] + bsv, acc[i][j][1] + bsv);
                ov[1] = pack2(acc[i][j][2] + bsv, acc[i][j][3] + bsv);
                *(u32x2*)&vto[(bh*HDIM + d)*SEQ + s] = ov;
            } else {
                unsigned short* o = (which == 0) ? qo : ko;
                #pragma unroll
                for (int r = 0; r < 4; ++r)
                    o[(bh*SEQ + (s + r))*HDIM + d] = f2bf((acc[i][j][r] + bsv) * kscale);
            }
        }
    }
}

// ------------------------------------------------------------------
// Kernel 2: flash attention (unchanged from R10/R11 best).
// ------------------------------------------------------------------
__global__ __launch_bounds__(256, 4) void attn(
    const unsigned short* __restrict__ q,
    const unsigned short* __restrict__ k,
    const unsigned short* __restrict__ vt,
    unsigned short* __restrict__ ctx)
{
    __shared__ __align__(16) unsigned char sm[2 * 16384];

    const int bid   = blockIdx.x;
    const int xcd   = bid & 7;
    const int local = bid >> 3;
    const int bh    = xcd * 4 + (local >> 5);
    const int q0    = (local & 31) * 64;
    const int b     = bh >> 4;
    const int h     = bh & (HEADS - 1);
    const int tid   = threadIdx.x;
    const int wv    = tid >> 6;
    const int lane  = tid & 63;
    const int lq = lane & 15, lg = lane >> 4;

    const unsigned short* qb = q  + (size_t)bh * SEQ * HDIM;
    const unsigned short* kb = k  + (size_t)bh * SEQ * HDIM;
    const unsigned short* vb = vt + (size_t)bh * HDIM * SEQ;

    const int swz    = (lq & 7) << 4;
    const int kread0 = lq*128 + ((lg*16)      ^ swz);
    const int kread1 = lq*128 + ((lg*16 + 64) ^ swz);

    const int vrd0 = lq*128 + ((lg*32)      ^ swz);
    const int vrd1 = lq*128 + ((lg*32 + 16) ^ swz);

    const int wrow = tid >> 3;
    const int c8   = tid & 7;
    const int wswz = (wrow & 7) << 4;
    const int woff = wrow*128 + ((c8 * 16) ^ wswz);
    const int vin0 = (c8 & 1)*64 + (c8 >> 1)*8;
    const int woffV0 = wrow*128 + (vin0        ^ wswz);
    const int woffV1 = wrow*128 + ((vin0 + 32) ^ wswz);

    const int scol = c8 * 8;
    const unsigned short* kp = kb + (size_t)wrow * HDIM + scol;
    const unsigned short* vp = vb + (size_t)wrow * SEQ + scol;

    bf16x8 qf[2];
    #pragma unroll
    for (int hh = 0; hh < 2; ++hh)
        qf[hh] = *(const bf16x8*)(qb + (size_t)(q0 + wv*16 + lq) * HDIM + hh*32 + lg*8);

    f32x4 o[4] = {};
    float lr = 0.f;

    u16x8 kr0, kr1, vr0, vr1;

#define LOADT() do {                                                           \
    kr0 = *(const u16x8*)(kp);                                                 \
    kr1 = *(const u16x8*)(kp + 32*HDIM);                                       \
    vr0 = *(const u16x8*)(vp);                                                 \
    vr1 = *(const u16x8*)(vp + 32*SEQ);                                        \
} while (0)

#define WRITET(BF) do {                                                        \
    unsigned char* smb = sm + (BF)*16384;                                      \
    *(u16x8*)(smb +        woff) = kr0;                                        \
    *(u16x8*)(smb + 4096 + woff) = kr1;                                        \
    u32x4 t0 = __builtin_bit_cast(u32x4, vr0);                                 \
    u32x4 t1 = __builtin_bit_cast(u32x4, vr1);                                 \
    u32x2 hlf;                                                                 \
    hlf[0] = t0[0]; hlf[1] = t0[1];                                            \
    *(u32x2*)(smb +  8192 + woffV0) = hlf;                                     \
    hlf[0] = t0[2]; hlf[1] = t0[3];                                            \
    *(u32x2*)(smb +  8192 + woffV1) = hlf;                                     \
    hlf[0] = t1[0]; hlf[1] = t1[1];                                            \
    *(u32x2*)(smb + 12288 + woffV0) = hlf;                                     \
    hlf[0] = t1[2]; hlf[1] = t1[3];                                            \
    *(u32x2*)(smb + 12288 + woffV1) = hlf;                                     \
} while (0)

#define COMPUTE(BF) do {                                                       \
    const unsigned char* smb = sm + (BF)*16384;                                \
    f32x4 s_[4];                                                               \
    _Pragma("unroll")                                                          \
    for (int sub = 0; sub < 4; ++sub) {                                        \
        bf16x8 k0 = *(const bf16x8*)(smb + sub*2048 + kread0);                 \
        bf16x8 k1 = *(const bf16x8*)(smb + sub*2048 + kread1);                 \
        f32x4 z = {};                                                          \
        z = __builtin_amdgcn_mfma_f32_16x16x32_bf16(k0, qf[0], z, 0, 0, 0);    \
        z = __builtin_amdgcn_mfma_f32_16x16x32_bf16(k1, qf[1], z, 0, 0, 0);    \
        s_[sub] = z;                                                           \
    }                                                                          \
    bf16x4 pf[4];                                                              \
    float psum = 0.f;                                                          \
    _Pragma("unroll")                                                          \
    for (int sub = 0; sub < 4; ++sub) {                                        \
        f32x4 pv;                                                              \
        _Pragma("unroll")                                                      \
        for (int r = 0; r < 4; ++r) pv[r] = exp2f(s_[sub][r]);                 \
        psum += (pv[0] + pv[1]) + (pv[2] + pv[3]);                             \
        u32x2 pk;                                                              \
        pk[0] = pack2(pv[0], pv[1]);                                           \
        pk[1] = pack2(pv[2], pv[3]);                                           \
        pf[sub] = __builtin_bit_cast(bf16x4, pk);                              \
    }                                                                          \
    lr += psum;                                                                \
    _Pragma("unroll")                                                          \
    for (int i = 0; i < 4; ++i) {                                              \
        bf16x8 v01 = *(const bf16x8*)(smb + 8192 + i*2048 + vrd0);             \
        bf16x8 v23 = *(const bf16x8*)(smb + 8192 + i*2048 + vrd1);             \
        u32x4 a01 = __builtin_bit_cast(u32x4, v01);                            \
        u32x4 a23 = __builtin_bit_cast(u32x4, v23);                            \
        u32x2 hw;                                                              \
        hw[0] = a01[0]; hw[1] = a01[1];                                        \
        o[i] = mfma16(__builtin_bit_cast(bf16x4, hw), pf[0], o[i]);            \
        hw[0] = a01[2]; hw[1] = a01[3];                                        \
        o[i] = mfma16(__builtin_bit_cast(bf16x4, hw), pf[1], o[i]);            \
        hw[0] = a23[0]; hw[1] = a23[1];                                        \
        o[i] = mfma16(__builtin_bit_cast(bf16x4, hw), pf[2], o[i]);            \
        hw[0] = a23[2]; hw[1] = a23[3];                                        \
        o[i] = mfma16(__builtin_bit_cast(bf16x4, hw), pf[3], o[i]);            \
    }                                                                          \
} while (0)

    LOADT();
    WRITET(0);
    __syncthreads();
    kp += 64 * HDIM;
    vp += 64;

    for (int t2 = 0; t2 < 16; ++t2) {
        {
            const int t = 2 * t2;
            if (t < 31) LOADT();
            COMPUTE(0);
            if (t < 31) {
                WRITET(1);
                __syncthreads();
                kp += 64 * HDIM;
                vp += 64;
            }
        }
        {
            const int t = 2 * t2 + 1;
            if (t < 31) LOADT();
            COMPUTE(1);
            if (t < 31) {
                WRITET(0);
                __syncthreads();
                kp += 64 * HDIM;
                vp += 64;
            }
        }
    }

#undef LOADT
#undef WRITET
#undef COMPUTE

    float lm = lr + __shfl_xor(lr, 16);
    lm += __shfl_xor(lm, 32);
    const float inv = 1.0f / lm;
    unsigned short* cb = ctx + ((size_t)(b*SEQ + q0 + wv*16 + lq)) * EMBED + h*HDIM;
    #pragma unroll
    for (int i = 0; i < 4; ++i) {
        u32x2 ov;
        ov[0] = pack2(o[i][0] * inv, o[i][1] * inv);
        ov[1] = pack2(o[i][2] * inv, o[i][3] * inv);
        *(u32x2*)(cb + i*16 + lg*4) = ov;
    }
}

// ------------------------------------------------------------------
// Kernel 3: output projection, m97-style staging (as qkv).
// ------------------------------------------------------------------
__global__ __launch_bounds__(256, 2) void out_proj(
    const unsigned short* __restrict__ ctx,
    const unsigned short* __restrict__ wob, const float* __restrict__ bo,
    float* __restrict__ out)
{
    const int m0 = blockIdx.x * 128;
    const int n0 = blockIdx.y * 128;

    __shared__ __align__(16) unsigned short a_lds[128 * 32];
    __shared__ __align__(16) unsigned short b_lds[128 * 32];

    const int tid  = threadIdx.x;
    const int lane = tid & 63;
    const int wid  = tid >> 6;
    const int wr   = wid >> 1, wc = wid & 1;
    const int lq   = lane & 15;
    const int lg   = lane >> 4;

    f32x4 acc[4][4] = {};

    const int srow  = wid * 32 + (lane >> 2);
    const int scol8 = (lane & 3) * 8;
    const unsigned short* ap0 = ctx + (size_t)(m0 + srow)      * EMBED + scol8;
    const unsigned short* ap1 = ctx + (size_t)(m0 + srow + 16) * EMBED + scol8;
    const unsigned short* bp0 = wob + (size_t)(n0 + srow)      * EMBED + scol8;
    const unsigned short* bp1 = wob + (size_t)(n0 + srow + 16) * EMBED + scol8;
    unsigned short* la0 = a_lds + wid * 1024;
    unsigned short* la1 = a_lds + wid * 1024 + 512;
    unsigned short* lb0 = b_lds + wid * 1024;
    unsigned short* lb1 = b_lds + wid * 1024 + 512;

    for (int k0 = 0; k0 < EMBED; k0 += 32) {
        glds16(ap0 + k0, la0);
        glds16(ap1 + k0, la1);
        glds16(bp0 + k0, lb0);
        glds16(bp1 + k0, lb1);
        __syncthreads();
        bf16x8 af[4], bfr[4];
        #pragma unroll
        for (int i = 0; i < 4; ++i)
            af[i] = *(const bf16x8*)&a_lds[(wr*64 + i*16 + lq) * 32 + lg*8];
        #pragma unroll
        for (int j = 0; j < 4; ++j)
            bfr[j] = *(const bf16x8*)&b_lds[(wc*64 + j*16 + lq) * 32 + lg*8];
        #pragma unroll
        for (int i = 0; i < 4; ++i)
            #pragma unroll
            for (int j = 0; j < 4; ++j)
                acc[i][j] = __builtin_amdgcn_mfma_f32_16x16x32_bf16(af[i], bfr[j], acc[i][j], 0, 0, 0);
        __syncthreads();
    }

    #pragma unroll
    for (int j = 0; j < 4; ++j) {
        const int nn = n0 + wc*64 + j*16 + lq;
        const float bsv = bo[nn];
        #pragma unroll
        for (int i = 0; i < 4; ++i) {
            const int mm = m0 + wr*64 + i*16 + lg*4;
            #pragma unroll
            for (int r = 0; r < 4; ++r)
                out[(size_t)(mm + r) * EMBED + nn] = acc[i][j][r] + bsv;
        }
    }
}

extern "C" void kernel_launch(void* const* d_in, const int* in_sizes, int n_in,
                              void* d_out, int out_size, void* d_ws, size_t ws_size,
                              hipStream_t stream) {
    const float* x  = (const float*)d_in[0];
    const float* wq = (const float*)d_in[1];
    const float* bq = (const float*)d_in[2];
    const float* wk = (const float*)d_in[3];
    const float* bk = (const float*)d_in[4];
    const float* wv = (const float*)d_in[5];
    const float* bv = (const float*)d_in[6];
    const float* wo = (const float*)d_in[7];
    const float* bo = (const float*)d_in[8];
    float* out = (float*)d_out;

    const size_t NELEM = (size_t)MTOT * EMBED;   // 4M elements
    const size_t WELEM = (size_t)EMBED * EMBED;  // 1M elements
    unsigned short* q_ws   = (unsigned short*)d_ws;
    unsigned short* k_ws   = q_ws  + NELEM;
    unsigned short* vt_ws  = k_ws  + NELEM;
    unsigned short* ctx_ws = vt_ws + NELEM;
    unsigned short* wqb    = ctx_ws + NELEM;
    unsigned short* wkb    = wqb + WELEM;
    unsigned short* wvb    = wkb + WELEM;
    unsigned short* wob    = wvb + WELEM;        // total 40 MB
    unsigned short* xb     = ctx_ws;             // alias: consumed before ctx written

    const int NCONV = (int)((NELEM + 4 * WELEM) / 4);
    preconvert<<<dim3(NCONV / 256), 256, 0, stream>>>(
        x, wq, wk, wv, wo, xb, wqb, wkb, wvb, wob);
    qkv_proj<<<dim3(MTOT/128, EMBED/128, 3), 256, 0, stream>>>(
        xb, wqb, bq, wkb, bk, wvb, bv, q_ws, k_ws, vt_ws);
    attn<<<dim3(SEQ/64 * BATCH*HEADS), 256, 0, stream>>>(q_ws, k_ws, vt_ws, ctx_ws);
    out_proj<<<dim3(MTOT/128, EMBED/128), 256, 0, stream>>>(ctx_ws, wob, bo, out);
}

// Round 13
// 134.823 us; speedup vs baseline: 2.4813x; 1.0306x over previous
//
#include <hip/hip_runtime.h>
#include <hip/hip_bf16.h>

#define EMBED 1024
#define HEADS 16
#define HDIM  64
#define BATCH 2
#define SEQ   2048
#define MTOT  (BATCH*SEQ)   // 4096

typedef __attribute__((ext_vector_type(8))) short bf16x8;
typedef __attribute__((ext_vector_type(4))) short bf16x4;
typedef __attribute__((ext_vector_type(4))) float f32x4;
typedef __attribute__((ext_vector_type(8))) unsigned short u16x8;
typedef __attribute__((ext_vector_type(2))) unsigned u32x2;
typedef __attribute__((ext_vector_type(4))) unsigned u32x4;

// native RNE f32->bf16 pair: compiles to one v_cvt_pk_bf16_f32
__device__ __forceinline__ unsigned pack2(float lo, float hi) {
    __hip_bfloat162 h = __float22bfloat162_rn(make_float2(lo, hi));
    unsigned u;
    __builtin_memcpy(&u, &h, sizeof(u));
    return u;
}
__device__ __forceinline__ unsigned short f2bf(float f) {
    __hip_bfloat16 h = __float2bfloat16(f);
    unsigned short u;
    __builtin_memcpy(&u, &h, sizeof(u));
    return u;
}

// async global->LDS DMA, 16B per lane (dest = lds base + lane*16)
__device__ __forceinline__ void glds16(const void* g, void* l) {
    __builtin_amdgcn_global_load_lds(
        (const __attribute__((address_space(1))) void*)g,
        (__attribute__((address_space(3))) void*)l, 16, 0, 0);
}

// ------------------------------------------------------------------
// Kernel 0: one-shot f32 -> bf16 conversion (unchanged).
// ------------------------------------------------------------------
__global__ __launch_bounds__(256) void preconvert(
    const float* __restrict__ x,
    const float* __restrict__ wq, const float* __restrict__ wk,
    const float* __restrict__ wv, const float* __restrict__ wo,
    unsigned short* __restrict__ xb,
    unsigned short* __restrict__ wqb, unsigned short* __restrict__ wkb,
    unsigned short* __restrict__ wvb, unsigned short* __restrict__ wob)
{
    const int NX = (MTOT * EMBED) / 4;
    const int NW = (EMBED * EMBED) / 4;
    int idx = blockIdx.x * 256 + threadIdx.x;
    const float* src;
    unsigned short* dst;
    int off;
    if (idx < NX) {
        src = x; dst = xb; off = idx;
    } else {
        int r = idx - NX;
        int w = r / NW;
        off = r - w * NW;
        src = (w == 0) ? wq : (w == 1) ? wk : (w == 2) ? wv : wo;
        dst = (w == 0) ? wqb : (w == 1) ? wkb : (w == 2) ? wvb : wob;
    }
    float4 v = ((const float4*)src)[off];
    u32x2 o;
    o[0] = pack2(v.x, v.y);
    o[1] = pack2(v.z, v.w);
    *(u32x2*)(dst + (size_t)off * 4) = o;
}

// ------------------------------------------------------------------
// Kernel 1: QKV projection (unchanged from R12: m97 global_load_lds
// staging; K pre-scaled by 0.125*log2e).
// ------------------------------------------------------------------
__global__ __launch_bounds__(256, 2) void qkv_proj(
    const unsigned short* __restrict__ xb,
    const unsigned short* __restrict__ wqb, const float* __restrict__ bq,
    const unsigned short* __restrict__ wkb, const float* __restrict__ bk,
    const unsigned short* __restrict__ wvb, const float* __restrict__ bv,
    unsigned short* __restrict__ qo,
    unsigned short* __restrict__ ko,
    unsigned short* __restrict__ vto)
{
    const int which = blockIdx.z;
    const unsigned short* __restrict__ w =
        (which == 0) ? wqb : (which == 1) ? wkb : wvb;
    const float* __restrict__ bias = (which == 0) ? bq : (which == 1) ? bk : bv;
    const float kscale = (which == 1) ? 0.18033688f : 1.0f;  // 0.125*log2e

    const int m0 = blockIdx.x * 128;
    const int n0 = blockIdx.y * 128;

    __shared__ __align__(16) unsigned short a_lds[128 * 32];
    __shared__ __align__(16) unsigned short b_lds[128 * 32];

    const int tid  = threadIdx.x;
    const int lane = tid & 63;
    const int wid  = tid >> 6;
    const int wr   = wid >> 1, wc = wid & 1;
    const int lq   = lane & 15;
    const int lg   = lane >> 4;

    f32x4 acc[4][4] = {};

    const int srow  = wid * 32 + (lane >> 2);
    const int scol8 = (lane & 3) * 8;
    const unsigned short* ap0 = xb + (size_t)(m0 + srow)      * EMBED + scol8;
    const unsigned short* ap1 = xb + (size_t)(m0 + srow + 16) * EMBED + scol8;
    const unsigned short* bp0 = w  + (size_t)(n0 + srow)      * EMBED + scol8;
    const unsigned short* bp1 = w  + (size_t)(n0 + srow + 16) * EMBED + scol8;
    unsigned short* la0 = a_lds + wid * 1024;
    unsigned short* la1 = a_lds + wid * 1024 + 512;
    unsigned short* lb0 = b_lds + wid * 1024;
    unsigned short* lb1 = b_lds + wid * 1024 + 512;

    for (int k0 = 0; k0 < EMBED; k0 += 32) {
        glds16(ap0 + k0, la0);
        glds16(ap1 + k0, la1);
        glds16(bp0 + k0, lb0);
        glds16(bp1 + k0, lb1);
        __syncthreads();
        bf16x8 af[4], bfr[4];
        #pragma unroll
        for (int i = 0; i < 4; ++i)
            af[i] = *(const bf16x8*)&a_lds[(wr*64 + i*16 + lq) * 32 + lg*8];
        #pragma unroll
        for (int j = 0; j < 4; ++j)
            bfr[j] = *(const bf16x8*)&b_lds[(wc*64 + j*16 + lq) * 32 + lg*8];
        #pragma unroll
        for (int i = 0; i < 4; ++i)
            #pragma unroll
            for (int j = 0; j < 4; ++j)
                acc[i][j] = __builtin_amdgcn_mfma_f32_16x16x32_bf16(af[i], bfr[j], acc[i][j], 0, 0, 0);
        __syncthreads();
    }

    #pragma unroll
    for (int j = 0; j < 4; ++j) {
        const int nn = n0 + wc*64 + j*16 + lq;
        const float bsv = bias[nn];
        const int h = nn >> 6, d = nn & (HDIM-1);
        #pragma unroll
        for (int i = 0; i < 4; ++i) {
            const int mmb = m0 + wr*64 + i*16 + lg*4;
            const int b = mmb >> 11;
            const int s = mmb & (SEQ-1);
            const size_t bh = (size_t)(b*HEADS + h);
            if (which == 2) {
                u32x2 ov;
                ov[0] = pack2(acc[i][j][0] + bsv, acc[i][j][1] + bsv);
                ov[1] = pack2(acc[i][j][2] + bsv, acc[i][j][3] + bsv);
                *(u32x2*)&vto[(bh*HDIM + d)*SEQ + s] = ov;
            } else {
                unsigned short* o = (which == 0) ? qo : ko;
                #pragma unroll
                for (int r = 0; r < 4; ++r)
                    o[(bh*SEQ + (s + r))*HDIM + d] = f2bf((acc[i][j][r] + bsv) * kscale);
            }
        }
    }
}

// ------------------------------------------------------------------
// Kernel 2: flash attention v10.
//  *** K-row-permuted QK^T -> PV as 16x16x32 with lane-local P ***
//  QK^T sub-tile `sub` reads K rows perm(sub,m)=8*(m>>2)+4*(sub&1)+
//  (m&3)+32*(sub>>1). Then lane lg's S^T registers hold exactly the
//  kv=lg*8+e slots the K=32 PV B-operand needs: pb0=[pf0|pf1],
//  pb1=[pf2|pf3]; PV = 8 MFMA (was 16), zero shuffles, V stored PLAIN
//  [64][64] (writes 2xb128, reads 8xb128 contiguous).
//  Row-hash swizzle S'(row)=(row&3)|(bit3<<2) keeps ALL patterns
//  bank-minimal (write: 8 col-slots/row; reads: S' spans 8 twice).
//  No online max (R8); dbuf; T14 pipeline; XCD swizzle.
// ------------------------------------------------------------------
__global__ __launch_bounds__(256, 4) void attn(
    const unsigned short* __restrict__ q,
    const unsigned short* __restrict__ k,
    const unsigned short* __restrict__ vt,
    unsigned short* __restrict__ ctx)
{
    __shared__ __align__(16) unsigned char sm[2 * 16384];  // per buf: K 8KB, V 8KB

    const int bid   = blockIdx.x;          // 0..1023
    const int xcd   = bid & 7;
    const int local = bid >> 3;            // 0..127
    const int bh    = xcd * 4 + (local >> 5);
    const int q0    = (local & 31) * 64;
    const int b     = bh >> 4;
    const int h     = bh & (HEADS - 1);
    const int tid   = threadIdx.x;
    const int wv    = tid >> 6;
    const int lane  = tid & 63;
    const int lq = lane & 15, lg = lane >> 4;

    const unsigned short* qb = q  + (size_t)bh * SEQ * HDIM;
    const unsigned short* kb = k  + (size_t)bh * SEQ * HDIM;
    const unsigned short* vb = vt + (size_t)bh * HDIM * SEQ;

    // ---- K-read offsets: row perm(sub,lq); swizzle S'(row) is
    // lane-constant across subs: (lq&3) | bit(lq,2)<<2 ----
    const int lg16 = lg * 16;
    const int Sp = (((lq & 3) | (((lq >> 2) & 1) << 2)) << 4);
    const int Tp = (((lq & 3) | (((lq >> 3) & 1) << 2)) << 4);
    const int kreadA = (8*(lq >> 2) + (lq & 3)) * 128 + (lg16 ^ Sp);  // d 0-31
    const int kreadB = kreadA ^ 64;                                    // d 32-63
    const int vreadA = lq * 128 + (lg16 ^ Tp);   // + i*2048, kv 0-31
    const int vreadB = vreadA ^ 64;              //            kv 32-63

    // ---- staging: identical offsets for K and V (different base) ----
    const int wrow = tid >> 3;             // 0..31
    const int c8   = tid & 7;              // 0..7
    const int wS   = (((wrow & 3) | (((wrow >> 3) & 1) << 2)) << 4);
    const int woff = wrow * 128 + ((c8 * 16) ^ wS);

    const int scol = c8 * 8;
    const unsigned short* kp = kb + (size_t)wrow * HDIM + scol;
    const unsigned short* vp = vb + (size_t)wrow * SEQ + scol;

    bf16x8 qf[2];
    #pragma unroll
    for (int hh = 0; hh < 2; ++hh)
        qf[hh] = *(const bf16x8*)(qb + (size_t)(q0 + wv*16 + lq) * HDIM + hh*32 + lg*8);

    f32x4 o[4] = {};
    float lr = 0.f;

    u16x8 kr0, kr1, vr0, vr1;

#define LOADT() do {                                                           \
    kr0 = *(const u16x8*)(kp);                                                 \
    kr1 = *(const u16x8*)(kp + 32*HDIM);                                       \
    vr0 = *(const u16x8*)(vp);                                                 \
    vr1 = *(const u16x8*)(vp + 32*SEQ);                                        \
} while (0)

#define WRITET(BF) do {                                                        \
    unsigned char* smb = sm + (BF)*16384;                                      \
    *(u16x8*)(smb +         woff) = kr0;                                       \
    *(u16x8*)(smb +  4096 + woff) = kr1;                                       \
    *(u16x8*)(smb +  8192 + woff) = vr0;                                       \
    *(u16x8*)(smb + 12288 + woff) = vr1;                                       \
} while (0)

#define COMPUTE(BF) do {                                                       \
    const unsigned char* smb = sm + (BF)*16384;                                \
    f32x4 s_[4];                                                               \
    _Pragma("unroll")                                                          \
    for (int sub = 0; sub < 4; ++sub) {                                        \
        const int sadd = (sub & 1) * 512 + (sub >> 1) * 4096;                  \
        bf16x8 k0 = *(const bf16x8*)(smb + sadd + kreadA);                     \
        bf16x8 k1 = *(const bf16x8*)(smb + sadd + kreadB);                     \
        f32x4 z = {};                                                          \
        z = __builtin_amdgcn_mfma_f32_16x16x32_bf16(k0, qf[0], z, 0, 0, 0);    \
        z = __builtin_amdgcn_mfma_f32_16x16x32_bf16(k1, qf[1], z, 0, 0, 0);    \
        s_[sub] = z;                                                           \
    }                                                                          \
    u32x4 pbw0, pbw1;                                                          \
    float psum = 0.f;                                                          \
    _Pragma("unroll")                                                          \
    for (int sub = 0; sub < 4; ++sub) {                                        \
        f32x4 pv;                                                              \
        _Pragma("unroll")                                                      \
        for (int r = 0; r < 4; ++r) pv[r] = exp2f(s_[sub][r]);                 \
        psum += (pv[0] + pv[1]) + (pv[2] + pv[3]);                             \
        unsigned d0 = pack2(pv[0], pv[1]);                                     \
        unsigned d1 = pack2(pv[2], pv[3]);                                     \
        if (sub == 0)      { pbw0[0] = d0; pbw0[1] = d1; }                     \
        else if (sub == 1) { pbw0[2] = d0; pbw0[3] = d1; }                     \
        else if (sub == 2) { pbw1[0] = d0; pbw1[1] = d1; }                     \
        else               { pbw1[2] = d0; pbw1[3] = d1; }                     \
    }                                                                          \
    lr += psum;                                                                \
    bf16x8 pb0 = __builtin_bit_cast(bf16x8, pbw0);                             \
    bf16x8 pb1 = __builtin_bit_cast(bf16x8, pbw1);                             \
    _Pragma("unroll")                                                          \
    for (int i = 0; i < 4; ++i) {                                              \
        bf16x8 va = *(const bf16x8*)(smb + 8192 + i*2048 + vreadA);            \
        bf16x8 vbq = *(const bf16x8*)(smb + 8192 + i*2048 + vreadB);           \
        o[i] = __builtin_amdgcn_mfma_f32_16x16x32_bf16(va,  pb0, o[i], 0, 0, 0); \
        o[i] = __builtin_amdgcn_mfma_f32_16x16x32_bf16(vbq, pb1, o[i], 0, 0, 0); \
    }                                                                          \
} while (0)

    LOADT();
    WRITET(0);
    __syncthreads();
    kp += 64 * HDIM;
    vp += 64;

    for (int t2 = 0; t2 < 16; ++t2) {
        {
            const int t = 2 * t2;
            if (t < 31) LOADT();
            COMPUTE(0);
            if (t < 31) {
                WRITET(1);
                __syncthreads();
                kp += 64 * HDIM;
                vp += 64;
            }
        }
        {
            const int t = 2 * t2 + 1;
            if (t < 31) LOADT();
            COMPUTE(1);
            if (t < 31) {
                WRITET(0);
                __syncthreads();
                kp += 64 * HDIM;
                vp += 64;
            }
        }
    }

#undef LOADT
#undef WRITET
#undef COMPUTE

    float lm = lr + __shfl_xor(lr, 16);
    lm += __shfl_xor(lm, 32);
    const float inv = 1.0f / lm;
    unsigned short* cb = ctx + ((size_t)(b*SEQ + q0 + wv*16 + lq)) * EMBED + h*HDIM;
    #pragma unroll
    for (int i = 0; i < 4; ++i) {
        u32x2 ov;
        ov[0] = pack2(o[i][0] * inv, o[i][1] * inv);
        ov[1] = pack2(o[i][2] * inv, o[i][3] * inv);
        *(u32x2*)(cb + i*16 + lg*4) = ov;
    }
}

// ------------------------------------------------------------------
// Kernel 3: output projection (unchanged from R12).
// ------------------------------------------------------------------
__global__ __launch_bounds__(256, 2) void out_proj(
    const unsigned short* __restrict__ ctx,
    const unsigned short* __restrict__ wob, const float* __restrict__ bo,
    float* __restrict__ out)
{
    const int m0 = blockIdx.x * 128;
    const int n0 = blockIdx.y * 128;

    __shared__ __align__(16) unsigned short a_lds[128 * 32];
    __shared__ __align__(16) unsigned short b_lds[128 * 32];

    const int tid  = threadIdx.x;
    const int lane = tid & 63;
    const int wid  = tid >> 6;
    const int wr   = wid >> 1, wc = wid & 1;
    const int lq   = lane & 15;
    const int lg   = lane >> 4;

    f32x4 acc[4][4] = {};

    const int srow  = wid * 32 + (lane >> 2);
    const int scol8 = (lane & 3) * 8;
    const unsigned short* ap0 = ctx + (size_t)(m0 + srow)      * EMBED + scol8;
    const unsigned short* ap1 = ctx + (size_t)(m0 + srow + 16) * EMBED + scol8;
    const unsigned short* bp0 = wob + (size_t)(n0 + srow)      * EMBED + scol8;
    const unsigned short* bp1 = wob + (size_t)(n0 + srow + 16) * EMBED + scol8;
    unsigned short* la0 = a_lds + wid * 1024;
    unsigned short* la1 = a_lds + wid * 1024 + 512;
    unsigned short* lb0 = b_lds + wid * 1024;
    unsigned short* lb1 = b_lds + wid * 1024 + 512;

    for (int k0 = 0; k0 < EMBED; k0 += 32) {
        glds16(ap0 + k0, la0);
        glds16(ap1 + k0, la1);
        glds16(bp0 + k0, lb0);
        glds16(bp1 + k0, lb1);
        __syncthreads();
        bf16x8 af[4], bfr[4];
        #pragma unroll
        for (int i = 0; i < 4; ++i)
            af[i] = *(const bf16x8*)&a_lds[(wr*64 + i*16 + lq) * 32 + lg*8];
        #pragma unroll
        for (int j = 0; j < 4; ++j)
            bfr[j] = *(const bf16x8*)&b_lds[(wc*64 + j*16 + lq) * 32 + lg*8];
        #pragma unroll
        for (int i = 0; i < 4; ++i)
            #pragma unroll
            for (int j = 0; j < 4; ++j)
                acc[i][j] = __builtin_amdgcn_mfma_f32_16x16x32_bf16(af[i], bfr[j], acc[i][j], 0, 0, 0);
        __syncthreads();
    }

    #pragma unroll
    for (int j = 0; j < 4; ++j) {
        const int nn = n0 + wc*64 + j*16 + lq;
        const float bsv = bo[nn];
        #pragma unroll
        for (int i = 0; i < 4; ++i) {
            const int mm = m0 + wr*64 + i*16 + lg*4;
            #pragma unroll
            for (int r = 0; r < 4; ++r)
                out[(size_t)(mm + r) * EMBED + nn] = acc[i][j][r] + bsv;
        }
    }
}

extern "C" void kernel_launch(void* const* d_in, const int* in_sizes, int n_in,
                              void* d_out, int out_size, void* d_ws, size_t ws_size,
                              hipStream_t stream) {
    const float* x  = (const float*)d_in[0];
    const float* wq = (const float*)d_in[1];
    const float* bq = (const float*)d_in[2];
    const float* wk = (const float*)d_in[3];
    const float* bk = (const float*)d_in[4];
    const float* wv = (const float*)d_in[5];
    const float* bv = (const float*)d_in[6];
    const float* wo = (const float*)d_in[7];
    const float* bo = (const float*)d_in[8];
    float* out = (float*)d_out;

    const size_t NELEM = (size_t)MTOT * EMBED;   // 4M elements
    const size_t WELEM = (size_t)EMBED * EMBED;  // 1M elements
    unsigned short* q_ws   = (unsigned short*)d_ws;
    unsigned short* k_ws   = q_ws  + NELEM;
    unsigned short* vt_ws  = k_ws  + NELEM;
    unsigned short* ctx_ws = vt_ws + NELEM;
    unsigned short* wqb    = ctx_ws + NELEM;
    unsigned short* wkb    = wqb + WELEM;
    unsigned short* wvb    = wkb + WELEM;
    unsigned short* wob    = wvb + WELEM;        // total 40 MB
    unsigned short* xb     = ctx_ws;             // alias: consumed before ctx written

    const int NCONV = (int)((NELEM + 4 * WELEM) / 4);
    preconvert<<<dim3(NCONV / 256), 256, 0, stream>>>(
        x, wq, wk, wv, wo, xb, wqb, wkb, wvb, wob);
    qkv_proj<<<dim3(MTOT/128, EMBED/128, 3), 256, 0, stream>>>(
        xb, wqb, bq, wkb, bk, wvb, bv, q_ws, k_ws, vt_ws);
    attn<<<dim3(SEQ/64 * BATCH*HEADS), 256, 0, stream>>>(q_ws, k_ws, vt_ws, ctx_ws);
    out_proj<<<dim3(MTOT/128, EMBED/128), 256, 0, stream>>>(ctx_ws, wob, bo, out);
}

// Round 14
// 130.585 us; speedup vs baseline: 2.5619x; 1.0325x over previous
//
#include <hip/hip_runtime.h>
#include <hip/hip_bf16.h>

#define EMBED 1024
#define HEADS 16
#define HDIM  64
#define BATCH 2
#define SEQ   2048
#define MTOT  (BATCH*SEQ)   // 4096

typedef __attribute__((ext_vector_type(8))) short bf16x8;
typedef __attribute__((ext_vector_type(4))) short bf16x4;
typedef __attribute__((ext_vector_type(4))) float f32x4;
typedef __attribute__((ext_vector_type(8))) unsigned short u16x8;
typedef __attribute__((ext_vector_type(2))) unsigned u32x2;
typedef __attribute__((ext_vector_type(4))) unsigned u32x4;

// native RNE f32->bf16 pair: compiles to one v_cvt_pk_bf16_f32
__device__ __forceinline__ unsigned pack2(float lo, float hi) {
    __hip_bfloat162 h = __float22bfloat162_rn(make_float2(lo, hi));
    unsigned u;
    __builtin_memcpy(&u, &h, sizeof(u));
    return u;
}
__device__ __forceinline__ unsigned short f2bf(float f) {
    __hip_bfloat16 h = __float2bfloat16(f);
    unsigned short u;
    __builtin_memcpy(&u, &h, sizeof(u));
    return u;
}

// async global->LDS DMA, 16B per lane (dest = lds base + lane*16)
__device__ __forceinline__ void glds16(const void* g, void* l) {
    __builtin_amdgcn_global_load_lds(
        (const __attribute__((address_space(1))) void*)g,
        (__attribute__((address_space(3))) void*)l, 16, 0, 0);
}

// ------------------------------------------------------------------
// Kernel 0: one-shot f32 -> bf16 conversion (unchanged).
// ------------------------------------------------------------------
__global__ __launch_bounds__(256) void preconvert(
    const float* __restrict__ x,
    const float* __restrict__ wq, const float* __restrict__ wk,
    const float* __restrict__ wv, const float* __restrict__ wo,
    unsigned short* __restrict__ xb,
    unsigned short* __restrict__ wqb, unsigned short* __restrict__ wkb,
    unsigned short* __restrict__ wvb, unsigned short* __restrict__ wob)
{
    const int NX = (MTOT * EMBED) / 4;
    const int NW = (EMBED * EMBED) / 4;
    int idx = blockIdx.x * 256 + threadIdx.x;
    const float* src;
    unsigned short* dst;
    int off;
    if (idx < NX) {
        src = x; dst = xb; off = idx;
    } else {
        int r = idx - NX;
        int w = r / NW;
        off = r - w * NW;
        src = (w == 0) ? wq : (w == 1) ? wk : (w == 2) ? wv : wo;
        dst = (w == 0) ? wqb : (w == 1) ? wkb : (w == 2) ? wvb : wob;
    }
    float4 v = ((const float4*)src)[off];
    u32x2 o;
    o[0] = pack2(v.x, v.y);
    o[1] = pack2(v.z, v.w);
    *(u32x2*)(dst + (size_t)off * 4) = o;
}

// ------------------------------------------------------------------
// Kernel 1: QKV projection (unchanged from R12/R13).
// ------------------------------------------------------------------
__global__ __launch_bounds__(256, 2) void qkv_proj(
    const unsigned short* __restrict__ xb,
    const unsigned short* __restrict__ wqb, const float* __restrict__ bq,
    const unsigned short* __restrict__ wkb, const float* __restrict__ bk,
    const unsigned short* __restrict__ wvb, const float* __restrict__ bv,
    unsigned short* __restrict__ qo,
    unsigned short* __restrict__ ko,
    unsigned short* __restrict__ vto)
{
    const int which = blockIdx.z;
    const unsigned short* __restrict__ w =
        (which == 0) ? wqb : (which == 1) ? wkb : wvb;
    const float* __restrict__ bias = (which == 0) ? bq : (which == 1) ? bk : bv;
    const float kscale = (which == 1) ? 0.18033688f : 1.0f;  // 0.125*log2e

    const int m0 = blockIdx.x * 128;
    const int n0 = blockIdx.y * 128;

    __shared__ __align__(16) unsigned short a_lds[128 * 32];
    __shared__ __align__(16) unsigned short b_lds[128 * 32];

    const int tid  = threadIdx.x;
    const int lane = tid & 63;
    const int wid  = tid >> 6;
    const int wr   = wid >> 1, wc = wid & 1;
    const int lq   = lane & 15;
    const int lg   = lane >> 4;

    f32x4 acc[4][4] = {};

    const int srow  = wid * 32 + (lane >> 2);
    const int scol8 = (lane & 3) * 8;
    const unsigned short* ap0 = xb + (size_t)(m0 + srow)      * EMBED + scol8;
    const unsigned short* ap1 = xb + (size_t)(m0 + srow + 16) * EMBED + scol8;
    const unsigned short* bp0 = w  + (size_t)(n0 + srow)      * EMBED + scol8;
    const unsigned short* bp1 = w  + (size_t)(n0 + srow + 16) * EMBED + scol8;
    unsigned short* la0 = a_lds + wid * 1024;
    unsigned short* la1 = a_lds + wid * 1024 + 512;
    unsigned short* lb0 = b_lds + wid * 1024;
    unsigned short* lb1 = b_lds + wid * 1024 + 512;

    for (int k0 = 0; k0 < EMBED; k0 += 32) {
        glds16(ap0 + k0, la0);
        glds16(ap1 + k0, la1);
        glds16(bp0 + k0, lb0);
        glds16(bp1 + k0, lb1);
        __syncthreads();
        bf16x8 af[4], bfr[4];
        #pragma unroll
        for (int i = 0; i < 4; ++i)
            af[i] = *(const bf16x8*)&a_lds[(wr*64 + i*16 + lq) * 32 + lg*8];
        #pragma unroll
        for (int j = 0; j < 4; ++j)
            bfr[j] = *(const bf16x8*)&b_lds[(wc*64 + j*16 + lq) * 32 + lg*8];
        #pragma unroll
        for (int i = 0; i < 4; ++i)
            #pragma unroll
            for (int j = 0; j < 4; ++j)
                acc[i][j] = __builtin_amdgcn_mfma_f32_16x16x32_bf16(af[i], bfr[j], acc[i][j], 0, 0, 0);
        __syncthreads();
    }

    #pragma unroll
    for (int j = 0; j < 4; ++j) {
        const int nn = n0 + wc*64 + j*16 + lq;
        const float bsv = bias[nn];
        const int h = nn >> 6, d = nn & (HDIM-1);
        #pragma unroll
        for (int i = 0; i < 4; ++i) {
            const int mmb = m0 + wr*64 + i*16 + lg*4;
            const int b = mmb >> 11;
            const int s = mmb & (SEQ-1);
            const size_t bh = (size_t)(b*HEADS + h);
            if (which == 2) {
                u32x2 ov;
                ov[0] = pack2(acc[i][j][0] + bsv, acc[i][j][1] + bsv);
                ov[1] = pack2(acc[i][j][2] + bsv, acc[i][j][3] + bsv);
                *(u32x2*)&vto[(bh*HDIM + d)*SEQ + s] = ov;
            } else {
                unsigned short* o = (which == 0) ? qo : ko;
                #pragma unroll
                for (int r = 0; r < 4; ++r)
                    o[(bh*SEQ + (s + r))*HDIM + d] = f2bf((acc[i][j][r] + bsv) * kscale);
            }
        }
    }
}

// ------------------------------------------------------------------
// Kernel 2: flash attention v11.
//  = R13 (K-row-permuted QK^T, K=32 PV, zero-conflict row-hash LDS)
//  + *** 2 q-frags per wave (32 q-rows) ***: the 16 LDS b128 reads per
//    tile now feed TWO q-frags -> per-CU LDS pipe time halves (51->26us),
//    which was the measured binding pipe.
//  + *** P-sum via ones-MFMA ***: l-accum = mfma(ones, pb) replaces 16
//    VALU adds/frag/tile AND the final shfl reduce (K=32 sums all kv).
//    Normalization now uses exactly the bf16 P that PV uses.
//  Grid 512 blocks (2/CU, 8 waves/CU).
// ------------------------------------------------------------------
__global__ __launch_bounds__(256, 2) void attn(
    const unsigned short* __restrict__ q,
    const unsigned short* __restrict__ k,
    const unsigned short* __restrict__ vt,
    unsigned short* __restrict__ ctx)
{
    __shared__ __align__(16) unsigned char sm[2 * 16384];  // per buf: K 8KB, V 8KB

    const int bid   = blockIdx.x;          // 0..511
    const int xcd   = bid & 7;
    const int local = bid >> 3;            // 0..63
    const int bh    = xcd * 4 + (local >> 4);
    const int q0    = (local & 15) * 128;  // 128 q-rows per block
    const int b     = bh >> 4;
    const int h     = bh & (HEADS - 1);
    const int tid   = threadIdx.x;
    const int wv    = tid >> 6;
    const int lane  = tid & 63;
    const int lq = lane & 15, lg = lane >> 4;

    const unsigned short* qb = q  + (size_t)bh * SEQ * HDIM;
    const unsigned short* kb = k  + (size_t)bh * SEQ * HDIM;
    const unsigned short* vb = vt + (size_t)bh * HDIM * SEQ;

    // K-read offsets: row perm(sub,lq) with lane-constant swizzle
    const int lg16 = lg * 16;
    const int Sp = (((lq & 3) | (((lq >> 2) & 1) << 2)) << 4);
    const int Tp = (((lq & 3) | (((lq >> 3) & 1) << 2)) << 4);
    const int kreadA = (8*(lq >> 2) + (lq & 3)) * 128 + (lg16 ^ Sp);  // d 0-31
    const int kreadB = kreadA ^ 64;                                    // d 32-63
    const int vreadA = lq * 128 + (lg16 ^ Tp);   // + i*2048, kv 0-31
    const int vreadB = vreadA ^ 64;              //            kv 32-63

    // staging offsets (identical for K and V tiles)
    const int wrow = tid >> 3;             // 0..31
    const int c8   = tid & 7;              // 0..7
    const int wS   = (((wrow & 3) | (((wrow >> 3) & 1) << 2)) << 4);
    const int woff = wrow * 128 + ((c8 * 16) ^ wS);

    const int scol = c8 * 8;
    const unsigned short* kp = kb + (size_t)wrow * HDIM + scol;
    const unsigned short* vp = vb + (size_t)wrow * SEQ + scol;

    // this wave's 32 q-rows: frag t at rows q0 + wv*32 + t*16 + lq
    bf16x8 qf[2][2];
    #pragma unroll
    for (int t = 0; t < 2; ++t)
        #pragma unroll
        for (int hh = 0; hh < 2; ++hh)
            qf[t][hh] = *(const bf16x8*)(qb + (size_t)(q0 + wv*32 + t*16 + lq) * HDIM + hh*32 + lg*8);

    // ones fragment (bf16 1.0 = 0x3F80) for the P-sum MFMA
    u16x8 ones_u;
    #pragma unroll
    for (int e = 0; e < 8; ++e) ones_u[e] = 0x3F80;
    const bf16x8 ones = __builtin_bit_cast(bf16x8, ones_u);

    f32x4 o[2][4] = {};
    f32x4 acc_l[2] = {};

    u16x8 kr0, kr1, vr0, vr1;

#define LOADT() do {                                                           \
    kr0 = *(const u16x8*)(kp);                                                 \
    kr1 = *(const u16x8*)(kp + 32*HDIM);                                       \
    vr0 = *(const u16x8*)(vp);                                                 \
    vr1 = *(const u16x8*)(vp + 32*SEQ);                                        \
} while (0)

#define WRITET(BF) do {                                                        \
    unsigned char* smb = sm + (BF)*16384;                                      \
    *(u16x8*)(smb +         woff) = kr0;                                       \
    *(u16x8*)(smb +  4096 + woff) = kr1;                                       \
    *(u16x8*)(smb +  8192 + woff) = vr0;                                       \
    *(u16x8*)(smb + 12288 + woff) = vr1;                                       \
} while (0)

#define COMPUTE(BF) do {                                                       \
    const unsigned char* smb = sm + (BF)*16384;                                \
    f32x4 s_[2][4];                                                            \
    _Pragma("unroll")                                                          \
    for (int sub = 0; sub < 4; ++sub) {                                        \
        const int sadd = (sub & 1) * 512 + (sub >> 1) * 4096;                  \
        bf16x8 k0 = *(const bf16x8*)(smb + sadd + kreadA);                     \
        bf16x8 k1 = *(const bf16x8*)(smb + sadd + kreadB);                     \
        _Pragma("unroll")                                                      \
        for (int t = 0; t < 2; ++t) {                                          \
            f32x4 z = {};                                                      \
            z = __builtin_amdgcn_mfma_f32_16x16x32_bf16(k0, qf[t][0], z, 0, 0, 0); \
            z = __builtin_amdgcn_mfma_f32_16x16x32_bf16(k1, qf[t][1], z, 0, 0, 0); \
            s_[t][sub] = z;                                                    \
        }                                                                      \
    }                                                                          \
    bf16x8 pb[2][2];                                                           \
    _Pragma("unroll")                                                          \
    for (int t = 0; t < 2; ++t) {                                              \
        u32x4 pw0, pw1;                                                        \
        _Pragma("unroll")                                                      \
        for (int sub = 0; sub < 4; ++sub) {                                    \
            f32x4 pv;                                                          \
            _Pragma("unroll")                                                  \
            for (int r = 0; r < 4; ++r) pv[r] = exp2f(s_[t][sub][r]);          \
            unsigned d0 = pack2(pv[0], pv[1]);                                 \
            unsigned d1 = pack2(pv[2], pv[3]);                                 \
            if (sub == 0)      { pw0[0] = d0; pw0[1] = d1; }                   \
            else if (sub == 1) { pw0[2] = d0; pw0[3] = d1; }                   \
            else if (sub == 2) { pw1[0] = d0; pw1[1] = d1; }                   \
            else               { pw1[2] = d0; pw1[3] = d1; }                   \
        }                                                                      \
        pb[t][0] = __builtin_bit_cast(bf16x8, pw0);                            \
        pb[t][1] = __builtin_bit_cast(bf16x8, pw1);                            \
        acc_l[t] = __builtin_amdgcn_mfma_f32_16x16x32_bf16(ones, pb[t][0], acc_l[t], 0, 0, 0); \
        acc_l[t] = __builtin_amdgcn_mfma_f32_16x16x32_bf16(ones, pb[t][1], acc_l[t], 0, 0, 0); \
    }                                                                          \
    _Pragma("unroll")                                                          \
    for (int i = 0; i < 4; ++i) {                                              \
        bf16x8 va  = *(const bf16x8*)(smb + 8192 + i*2048 + vreadA);           \
        bf16x8 vbq = *(const bf16x8*)(smb + 8192 + i*2048 + vreadB);           \
        _Pragma("unroll")                                                      \
        for (int t = 0; t < 2; ++t) {                                          \
            o[t][i] = __builtin_amdgcn_mfma_f32_16x16x32_bf16(va,  pb[t][0], o[t][i], 0, 0, 0); \
            o[t][i] = __builtin_amdgcn_mfma_f32_16x16x32_bf16(vbq, pb[t][1], o[t][i], 0, 0, 0); \
        }                                                                      \
    }                                                                          \
} while (0)

    LOADT();
    WRITET(0);
    __syncthreads();
    kp += 64 * HDIM;
    vp += 64;

    for (int t2 = 0; t2 < 16; ++t2) {
        {
            const int t = 2 * t2;
            if (t < 31) LOADT();
            COMPUTE(0);
            if (t < 31) {
                WRITET(1);
                __syncthreads();
                kp += 64 * HDIM;
                vp += 64;
            }
        }
        {
            const int t = 2 * t2 + 1;
            if (t < 31) LOADT();
            COMPUTE(1);
            if (t < 31) {
                WRITET(0);
                __syncthreads();
                kp += 64 * HDIM;
                vp += 64;
            }
        }
    }

#undef LOADT
#undef WRITET
#undef COMPUTE

    // acc_l[t] holds (in every register) the full P-sum for q-row lq:
    // normalize and write. No cross-lane reduce needed.
    #pragma unroll
    for (int t = 0; t < 2; ++t) {
        const float inv = 1.0f / acc_l[t][0];
        unsigned short* cb = ctx + ((size_t)(b*SEQ + q0 + wv*32 + t*16 + lq)) * EMBED + h*HDIM;
        #pragma unroll
        for (int i = 0; i < 4; ++i) {
            u32x2 ov;
            ov[0] = pack2(o[t][i][0] * inv, o[t][i][1] * inv);
            ov[1] = pack2(o[t][i][2] * inv, o[t][i][3] * inv);
            *(u32x2*)(cb + i*16 + lg*4) = ov;
        }
    }
}

// ------------------------------------------------------------------
// Kernel 3: output projection (unchanged from R12/R13).
// ------------------------------------------------------------------
__global__ __launch_bounds__(256, 2) void out_proj(
    const unsigned short* __restrict__ ctx,
    const unsigned short* __restrict__ wob, const float* __restrict__ bo,
    float* __restrict__ out)
{
    const int m0 = blockIdx.x * 128;
    const int n0 = blockIdx.y * 128;

    __shared__ __align__(16) unsigned short a_lds[128 * 32];
    __shared__ __align__(16) unsigned short b_lds[128 * 32];

    const int tid  = threadIdx.x;
    const int lane = tid & 63;
    const int wid  = tid >> 6;
    const int wr   = wid >> 1, wc = wid & 1;
    const int lq   = lane & 15;
    const int lg   = lane >> 4;

    f32x4 acc[4][4] = {};

    const int srow  = wid * 32 + (lane >> 2);
    const int scol8 = (lane & 3) * 8;
    const unsigned short* ap0 = ctx + (size_t)(m0 + srow)      * EMBED + scol8;
    const unsigned short* ap1 = ctx + (size_t)(m0 + srow + 16) * EMBED + scol8;
    const unsigned short* bp0 = wob + (size_t)(n0 + srow)      * EMBED + scol8;
    const unsigned short* bp1 = wob + (size_t)(n0 + srow + 16) * EMBED + scol8;
    unsigned short* la0 = a_lds + wid * 1024;
    unsigned short* la1 = a_lds + wid * 1024 + 512;
    unsigned short* lb0 = b_lds + wid * 1024;
    unsigned short* lb1 = b_lds + wid * 1024 + 512;

    for (int k0 = 0; k0 < EMBED; k0 += 32) {
        glds16(ap0 + k0, la0);
        glds16(ap1 + k0, la1);
        glds16(bp0 + k0, lb0);
        glds16(bp1 + k0, lb1);
        __syncthreads();
        bf16x8 af[4], bfr[4];
        #pragma unroll
        for (int i = 0; i < 4; ++i)
            af[i] = *(const bf16x8*)&a_lds[(wr*64 + i*16 + lq) * 32 + lg*8];
        #pragma unroll
        for (int j = 0; j < 4; ++j)
            bfr[j] = *(const bf16x8*)&b_lds[(wc*64 + j*16 + lq) * 32 + lg*8];
        #pragma unroll
        for (int i = 0; i < 4; ++i)
            #pragma unroll
            for (int j = 0; j < 4; ++j)
                acc[i][j] = __builtin_amdgcn_mfma_f32_16x16x32_bf16(af[i], bfr[j], acc[i][j], 0, 0, 0);
        __syncthreads();
    }

    #pragma unroll
    for (int j = 0; j < 4; ++j) {
        const int nn = n0 + wc*64 + j*16 + lq;
        const float bsv = bo[nn];
        #pragma unroll
        for (int i = 0; i < 4; ++i) {
            const int mm = m0 + wr*64 + i*16 + lg*4;
            #pragma unroll
            for (int r = 0; r < 4; ++r)
                out[(size_t)(mm + r) * EMBED + nn] = acc[i][j][r] + bsv;
        }
    }
}

extern "C" void kernel_launch(void* const* d_in, const int* in_sizes, int n_in,
                              void* d_out, int out_size, void* d_ws, size_t ws_size,
                              hipStream_t stream) {
    const float* x  = (const float*)d_in[0];
    const float* wq = (const float*)d_in[1];
    const float* bq = (const float*)d_in[2];
    const float* wk = (const float*)d_in[3];
    const float* bk = (const float*)d_in[4];
    const float* wv = (const float*)d_in[5];
    const float* bv = (const float*)d_in[6];
    const float* wo = (const float*)d_in[7];
    const float* bo = (const float*)d_in[8];
    float* out = (float*)d_out;

    const size_t NELEM = (size_t)MTOT * EMBED;   // 4M elements
    const size_t WELEM = (size_t)EMBED * EMBED;  // 1M elements
    unsigned short* q_ws   = (unsigned short*)d_ws;
    unsigned short* k_ws   = q_ws  + NELEM;
    unsigned short* vt_ws  = k_ws  + NELEM;
    unsigned short* ctx_ws = vt_ws + NELEM;
    unsigned short* wqb    = ctx_ws + NELEM;
    unsigned short* wkb    = wqb + WELEM;
    unsigned short* wvb    = wkb + WELEM;
    unsigned short* wob    = wvb + WELEM;        // total 40 MB
    unsigned short* xb     = ctx_ws;             // alias: consumed before ctx written

    const int NCONV = (int)((NELEM + 4 * WELEM) / 4);
    preconvert<<<dim3(NCONV / 256), 256, 0, stream>>>(
        x, wq, wk, wv, wo, xb, wqb, wkb, wvb, wob);
    qkv_proj<<<dim3(MTOT/128, EMBED/128, 3), 256, 0, stream>>>(
        xb, wqb, bq, wkb, bk, wvb, bv, q_ws, k_ws, vt_ws);
    attn<<<dim3((SEQ/128) * BATCH*HEADS), 256, 0, stream>>>(q_ws, k_ws, vt_ws, ctx_ws);
    out_proj<<<dim3(MTOT/128, EMBED/128), 256, 0, stream>>>(ctx_ws, wob, bo, out);
}